// Round 13
// baseline (297.214 us; speedup 1.0000x reference)
//
#include <hip/hip_runtime.h>
#include <stdint.h>

#define NLAYERS 6
#define DD      128   // patch dim
#define CONDD   128
#define HID     256
#define DIN     192
#define TM      32    // tokens per block (4-wave blocks)
#define NTHR    256   // 4 waves
#define SA      72    // bufA row stride (elements): 64 + 8 pad
#define SB      264   // bufB/C row stride (elements): 256 + 8 pad

typedef __attribute__((ext_vector_type(4))) float f32x4;
typedef __attribute__((ext_vector_type(8))) short short8;
typedef __attribute__((ext_vector_type(2))) uint32_t u32x2;

// packed-weight geometry (16x16x32 bf16 MFMA B-fragments)
#define G1_KS 2
#define G2_KS 8
#define G3_KS 8
#define G1_FR (G1_KS*16)             // 32 frags
#define G2_FR (G2_KS*16)             // 128
#define G3_FR (G3_KS*8)              // 64
#define FR_L  (G1_FR+G2_FR+G3_FR)    // 224 frags / layer
#define EL_L  (FR_L*512)             // bf16 elems / layer
#define G2_OFF (G1_FR*512)
#define G3_OFF ((G1_FR+G2_FR)*512)

__device__ __forceinline__ short f2bf(float f) {   // fp32 -> bf16 (RNE), scalar
  uint32_t u = __builtin_bit_cast(uint32_t, f);
  u += 0x7fffu + ((u >> 16) & 1u);
  return (short)(u >> 16);
}
// HW packed convert: dst = {bf16(hi),bf16(lo)} in one instruction
__device__ __forceinline__ uint32_t cvtpk(float lo, float hi) {
  uint32_t r;
  asm("v_cvt_pk_bf16_f32 %0, %1, %2" : "=v"(r) : "v"(lo), "v"(hi));
  return r;
}
__device__ __forceinline__ float bfunpack(uint32_t p, int hi) { // elem 0=lo,1=hi
  return __builtin_bit_cast(float, hi ? (p & 0xffff0000u) : (p << 16));
}
// κ₂⁻¹: phys position p in a κ₂-packed 256-wide h-buffer -> logical feature.
// Writer thread (nq,l15) stores its 4 outputs contiguously: phys 64nq+4*l15+idx
// holds logical 64nq+16*idx+l15  (enables one b64 write per (m2,r)).
__device__ __forceinline__ int kinv2(int p) {
  return (p & ~63) | ((p & 3) << 4) | ((p >> 2) & 15);
}

// Pack weights into bf16 MFMA B-fragment layout.
// W2/W3 K-rows permuted by κ₂⁻¹ (they consume κ₂-packed h1/h2).
// W3 output cols: frag (2g+h), lane-lo lv -> logical col c_l + 64h where
// c_l = (lay even) ? 16g+lv : 63-(16g+lv)  (label-flip coupling).
__global__ void prep_weights(const float* __restrict__ W1,
                             const float* __restrict__ W2,
                             const float* __restrict__ W3,
                             short* __restrict__ wp)
{
  int t = blockIdx.x * 256 + threadIdx.x;      // 6*224*64 = 86016 threads exactly
  int lay  = t / (FR_L * 64);
  int rem  = t - lay * (FR_L * 64);
  int frag = rem >> 6;
  int lane = rem & 63;
  const float* src;
  int N, f2, dstbase, nfr, perm;
  if (frag < G1_FR) {
    f2 = frag;                  src = W1 + (size_t)lay * DIN * HID; N = HID; dstbase = 0;      nfr = 16; perm = 0;
  } else if (frag < G1_FR + G2_FR) {
    f2 = frag - G1_FR;          src = W2 + (size_t)lay * HID * HID; N = HID; dstbase = G2_OFF; nfr = 16; perm = 1;
  } else {
    f2 = frag - (G1_FR + G2_FR);src = W3 + (size_t)lay * HID * DD;  N = DD;  dstbase = G3_OFF; nfr = 8;  perm = 2;
  }
  int ks = f2 / nfr, nf = f2 - ks * nfr;
  int lv = lane & 15;
  int n;
  if (perm == 2) {               // σ_l: pair (s,t) for the same logical col c_l
    int g = nf >> 1, h = nf & 1;
    int c = 16 * g + lv;
    if (lay & 1) c = 63 - c;
    n = c + 64 * h;
  } else {
    n = nf * 16 + lv;
  }
  int k0 = ks * 32 + (lane >> 4) * 8;
  short8 v;
#pragma unroll
  for (int j = 0; j < 8; ++j) {
    int k = perm ? kinv2(k0 + j) : (k0 + j);
    v[j] = f2bf(src[(size_t)k * N + n]);
  }
  *(short8*)(wp + (size_t)lay * EL_L + dstbase + ((size_t)f2 * 64 + lane) * 8) = v;
}

// c1[lay][batch][h] = cond[batch] @ W1[lay][64:192][h] + b1[lay][h]  (fp32, logical h)
__global__ void prep_c1(const float* __restrict__ cond, const float* __restrict__ W1,
                        const float* __restrict__ b1, float* __restrict__ c1)
{
  int lay = blockIdx.x >> 9;
  int b   = blockIdx.x & 511;
  int h   = threadIdx.x;
  const float* wb = W1 + (size_t)lay * DIN * HID + 64 * HID + h;
  const float* cb = cond + b * CONDD;
  float acc = b1[lay * HID + h];
#pragma unroll 4
  for (int c = 0; c < CONDD; ++c) acc = fmaf(cb[c], wb[(size_t)c * HID], acc);
  c1[((size_t)lay * 512 + b) * HID + h] = acc;
}

__global__ __launch_bounds__(NTHR, 4)
void flow_kernel(const float* __restrict__ x,
                 const float* __restrict__ c1g, const float* __restrict__ b2g,
                 const float* __restrict__ b3g, const short* __restrict__ wp,
                 float* __restrict__ outz, float* __restrict__ outld)
{
  __shared__ alignas(16) short bufA[TM * SA];    // x1 bf16.           4.5KB
  __shared__ alignas(16) short bufB[TM * SB];    // h1 bf16 κ₂-packed. 16.5KB
  __shared__ alignas(16) short bufC[TM * SB];    // h2 bf16 κ₂-packed. 16.5KB
  __shared__ float red[4];

  const int tid  = threadIdx.x;
  const int wave = tid >> 6;                 // = col-quarter nq (0..3)
  const int lane = tid & 63;
  const int l15  = lane & 15;
  const int l4   = lane >> 4;
  const int nq   = wave;
  const int t0   = blockIdx.x * TM;
  const int batch = t0 >> 7;                 // 4 blocks per batch

  // z ownership: thread holds the dim-pair (c_l, 64+c_l) of its 8 rows,
  // c_0 = 16*nq + l15, c_{l+1} = 63 - c_l (label flip, no data motion).
  // x1 half (zlo) stays fp32; x2 half (zhiP) packed bf16x2 to free VGPRs.
  const int cB = 16 * nq + l15;
  const int rbase = 4 * l4;                  // rows rbase + 16*m2 + r (0..31)
  float zlo[8];
  uint32_t zhiP[4];                          // pairs (j=2p, 2p+1)
  short8 g1pre[4];                           // prefetched G1 ks=0 weight frags
  {
    const float* xb = x + (size_t)t0 * DD;
    float zt[8];
#pragma unroll
    for (int m2 = 0; m2 < 2; ++m2)
#pragma unroll
      for (int r = 0; r < 4; ++r) {
        int j = m2 * 4 + r;
        int row = rbase + 16 * m2 + r;
        zlo[j] = xb[row * DD + cB];
        zt[j]  = xb[row * DD + 64 + cB];
      }
#pragma unroll
    for (int p = 0; p < 4; ++p) zhiP[p] = cvtpk(zt[2 * p], zt[2 * p + 1]);
#pragma unroll
    for (int m2 = 0; m2 < 2; ++m2)           // stage x1 (bf16) for layer 0
#pragma unroll
      for (int r = 0; r < 4; ++r) {
        int row = rbase + 16 * m2 + r;
        bufA[row * SA + cB] = f2bf(zlo[m2 * 4 + r]);
      }
#pragma unroll
    for (int nf = 0; nf < 4; ++nf)           // prefetch G1(lay 0) ks=0 weights
      g1pre[nf] = *(const short8*)(wp + (((4 * nq + nf) * 64 + lane) * 8));
  }
  float ldsum = 0.f;
  __syncthreads();

#pragma unroll 1
  for (int lay = 0; lay < NLAYERS; ++lay) {
    const short* wl = wp + (size_t)lay * EL_L;
    const int cl = (lay & 1) ? (63 - cB) : cB;   // this layer's owned column
    short8 g2pre[4], g3pre[2];

    // ---- GEMM1: [32x64] @ W1a[64x256], bias acc-init, relu -> bufB (κ₂) ----
    {
      const float* c1row = c1g + ((size_t)lay * 512 + batch) * HID;
      f32x4 acc[2][4];
#pragma unroll
      for (int nf = 0; nf < 4; ++nf) {       // acc init = bias (C/D col = lane&15)
        float b = c1row[64 * nq + 16 * nf + l15];
        f32x4 bi = {b, b, b, b};
        acc[0][nf] = bi; acc[1][nf] = bi;
      }
      short8 nb1[4];                         // ks=1 weights (load during ks=0)
#pragma unroll
      for (int nf = 0; nf < 4; ++nf)
        nb1[nf] = *(const short8*)(wl + (((16 + 4 * nq + nf) * 64 + lane) * 8));
#pragma unroll
      for (int m2 = 0; m2 < 2; ++m2) {       // ks=0 with prefetched g1pre
        int row = 16 * m2 + l15;
        short8 a = *(const short8*)(bufA + row * SA + l4 * 8);
#pragma unroll
        for (int nf = 0; nf < 4; ++nf)
          acc[m2][nf] = __builtin_amdgcn_mfma_f32_16x16x32_bf16(a, g1pre[nf], acc[m2][nf], 0, 0, 0);
      }
#pragma unroll
      for (int m2 = 0; m2 < 2; ++m2) {       // ks=1
        int row = 16 * m2 + l15;
        short8 a = *(const short8*)(bufA + row * SA + 32 + l4 * 8);
#pragma unroll
        for (int nf = 0; nf < 4; ++nf)
          acc[m2][nf] = __builtin_amdgcn_mfma_f32_16x16x32_bf16(a, nb1[nf], acc[m2][nf], 0, 0, 0);
      }
#pragma unroll
      for (int m2 = 0; m2 < 2; ++m2)         // κ₂-packed b64 writes
#pragma unroll
        for (int r = 0; r < 4; ++r) {
          int row = rbase + 16 * m2 + r;
          u32x2 val = {cvtpk(fmaxf(acc[m2][0][r], 0.f), fmaxf(acc[m2][1][r], 0.f)),
                       cvtpk(fmaxf(acc[m2][2][r], 0.f), fmaxf(acc[m2][3][r], 0.f))};
          *(u32x2*)(bufB + row * SB + 64 * nq + 4 * l15) = val;
        }
#pragma unroll
      for (int nf = 0; nf < 4; ++nf)         // prefetch G2 ks=0 (in flight over B1)
        g2pre[nf] = *(const short8*)(wl + G2_OFF + (((4 * nq + nf) * 64 + lane) * 8));
    }
    __syncthreads();                         // B1: h1 ready

    // ---- GEMM2: bufB(h1) @ W2, bias-init, relu -> bufC (κ₂) ----
    {
      const short* wg = wl + G2_OFF;
      f32x4 acc[2][4];
#pragma unroll
      for (int nf = 0; nf < 4; ++nf) {
        float b = b2g[lay * HID + 64 * nq + 16 * nf + l15];
        f32x4 bi = {b, b, b, b};
        acc[0][nf] = bi; acc[1][nf] = bi;
      }
#pragma unroll
      for (int m2 = 0; m2 < 2; ++m2) {       // peeled ks=0 with prefetched g2pre
        int row = 16 * m2 + l15;
        short8 a = *(const short8*)(bufB + row * SB + l4 * 8);
#pragma unroll
        for (int nf = 0; nf < 4; ++nf)
          acc[m2][nf] = __builtin_amdgcn_mfma_f32_16x16x32_bf16(a, g2pre[nf], acc[m2][nf], 0, 0, 0);
      }
#pragma unroll 2
      for (int ks = 1; ks < G2_KS; ++ks) {   // R11-style in-loop loads
        short8 bb[4];
#pragma unroll
        for (int nf = 0; nf < 4; ++nf)
          bb[nf] = *(const short8*)(wg + (((ks * 16 + 4 * nq + nf) * 64 + lane) * 8));
#pragma unroll
        for (int m2 = 0; m2 < 2; ++m2) {
          int row = 16 * m2 + l15;
          short8 a = *(const short8*)(bufB + row * SB + ks * 32 + l4 * 8);
#pragma unroll
          for (int nf = 0; nf < 4; ++nf)
            acc[m2][nf] = __builtin_amdgcn_mfma_f32_16x16x32_bf16(a, bb[nf], acc[m2][nf], 0, 0, 0);
        }
      }
#pragma unroll
      for (int m2 = 0; m2 < 2; ++m2)
#pragma unroll
        for (int r = 0; r < 4; ++r) {
          int row = rbase + 16 * m2 + r;
          u32x2 val = {cvtpk(fmaxf(acc[m2][0][r], 0.f), fmaxf(acc[m2][1][r], 0.f)),
                       cvtpk(fmaxf(acc[m2][2][r], 0.f), fmaxf(acc[m2][3][r], 0.f))};
          *(u32x2*)(bufC + row * SB + 64 * nq + 4 * l15) = val;
        }
#pragma unroll
      for (int nf = 0; nf < 2; ++nf)         // prefetch G3 ks=0 (in flight over B2)
        g3pre[nf] = *(const short8*)(wl + G3_OFF + (((2 * nq + nf) * 64 + lane) * 8));
    }
    __syncthreads();                         // B2: h2 ready

    // ---- GEMM3 + coupling in registers (σ_l-paired s,t; label flip) ----
    {
      f32x4 acc3[2][2];
      {
        float bs = b3g[lay * DD + cl];
        float bt = b3g[lay * DD + 64 + cl];
        f32x4 bsi = {bs, bs, bs, bs}, bti = {bt, bt, bt, bt};
        acc3[0][0] = bsi; acc3[1][0] = bsi;
        acc3[0][1] = bti; acc3[1][1] = bti;
      }
#pragma unroll
      for (int m2 = 0; m2 < 2; ++m2) {       // peeled ks=0 with prefetched g3pre
        int row = 16 * m2 + l15;
        short8 a = *(const short8*)(bufC + row * SB + l4 * 8);
        acc3[m2][0] = __builtin_amdgcn_mfma_f32_16x16x32_bf16(a, g3pre[0], acc3[m2][0], 0, 0, 0);
        acc3[m2][1] = __builtin_amdgcn_mfma_f32_16x16x32_bf16(a, g3pre[1], acc3[m2][1], 0, 0, 0);
      }
#pragma unroll 2
      for (int ks = 1; ks < G3_KS; ++ks) {
        short8 bb[2];
#pragma unroll
        for (int nf = 0; nf < 2; ++nf)
          bb[nf] = *(const short8*)(wl + G3_OFF + (((ks * 8 + 2 * nq + nf) * 64 + lane) * 8));
#pragma unroll
        for (int m2 = 0; m2 < 2; ++m2) {
          int row = 16 * m2 + l15;
          short8 a = *(const short8*)(bufC + row * SB + ks * 32 + l4 * 8);
          acc3[m2][0] = __builtin_amdgcn_mfma_f32_16x16x32_bf16(a, bb[0], acc3[m2][0], 0, 0, 0);
          acc3[m2][1] = __builtin_amdgcn_mfma_f32_16x16x32_bf16(a, bb[1], acc3[m2][1], 0, 0, 0);
        }
      }
      // coupling: y2 = x2*exp(s)+t.  Label flip c->63-c: new (zlo,zhi) =
      // (y2, old x1) with NO cross-lane exchange.  zhi kept packed bf16x2.
#pragma unroll
      for (int m2 = 0; m2 < 2; ++m2)
#pragma unroll
        for (int rp = 0; rp < 2; ++rp) {
          int p = m2 * 2 + rp;
          float y2v[2];
#pragma unroll
          for (int e = 0; e < 2; ++e) {
            int r = 2 * rp + e;
            float sr = fminf(fmaxf(acc3[m2][0][r], -8.f), 8.f);
            float tt = acc3[m2][1][r];
            float e2 = __expf(2.f * sr);
            float s  = 0.5f * (e2 - 1.f) / (e2 + 1.f);   // 0.5*tanh(sr)
            ldsum += s;
            float x2 = bfunpack(zhiP[p], e);
            y2v[e] = fmaf(x2, __expf(s), tt);
          }
          int j0 = m2 * 4 + 2 * rp;
          zhiP[p]     = cvtpk(zlo[j0], zlo[j0 + 1]);   // new x2 = old x1
          zlo[j0]     = y2v[0];                        // new x1 = y2
          zlo[j0 + 1] = y2v[1];
        }
      if (lay < NLAYERS - 1) {
        const short* wn = wl + EL_L;         // next layer's weights
#pragma unroll
        for (int nf = 0; nf < 4; ++nf)       // prefetch next G1 ks=0 (over B3)
          g1pre[nf] = *(const short8*)(wn + (((4 * nq + nf) * 64 + lane) * 8));
        int cn = 63 - cl;                    // next layer's owned column
#pragma unroll
        for (int m2 = 0; m2 < 2; ++m2)       // stage next layer's x1 (bf16)
#pragma unroll
          for (int r = 0; r < 4; ++r) {
            int row = rbase + 16 * m2 + r;
            bufA[row * SA + cn] = f2bf(zlo[m2 * 4 + r]);
          }
        __syncthreads();                     // B3: bufA staged; h2 reads done
      }
    }
  }

  { // store z (c_6 = cB after 6 label flips)
    float* ob = outz + (size_t)t0 * DD;
#pragma unroll
    for (int m2 = 0; m2 < 2; ++m2)
#pragma unroll
      for (int r = 0; r < 4; ++r) {
        int j = m2 * 4 + r;
        int row = rbase + 16 * m2 + r;
        ob[row * DD + cB]      = zlo[j];
        ob[row * DD + 64 + cB] = bfunpack(zhiP[j >> 1], j & 1);
      }
  }
  // logdet: wave shuffle-reduce -> block -> one atomic (4 blocks/batch, commutative)
#pragma unroll
  for (int off = 32; off > 0; off >>= 1) ldsum += __shfl_down(ldsum, off);
  if (lane == 0) red[wave] = ldsum;
  __syncthreads();
  if (tid == 0) {
    float s = red[0] + red[1] + red[2] + red[3];
    atomicAdd(&outld[batch], s);
  }
}

extern "C" void kernel_launch(void* const* d_in, const int* in_sizes, int n_in,
                              void* d_out, int out_size, void* d_ws, size_t ws_size,
                              hipStream_t stream)
{
  (void)in_sizes; (void)n_in; (void)out_size; (void)ws_size;
  const float* x   = (const float*)d_in[0];
  const float* cnd = (const float*)d_in[1];
  const float* W1  = (const float*)d_in[2];
  const float* b1  = (const float*)d_in[3];
  const float* W2  = (const float*)d_in[4];
  const float* b2  = (const float*)d_in[5];
  const float* W3  = (const float*)d_in[6];
  const float* b3  = (const float*)d_in[7];
  float* outz  = (float*)d_out;
  float* outld = outz + (size_t)512 * 128 * 128;
  short* wp = (short*)d_ws;                            // 1.38 MB packed bf16 weights
  float* c1 = (float*)((char*)d_ws + (2u << 20));      // 3.1 MB fp32 cond-bias

  hipMemsetAsync(outld, 0, 512 * sizeof(float), stream);
  prep_weights<<<336, 256, 0, stream>>>(W1, W2, W3, wp);
  prep_c1<<<6 * 512, 256, 0, stream>>>(cnd, W1, b1, c1);
  flow_kernel<<<2048, NTHR, 0, stream>>>(x, c1, b2, b3, wp, outz, outld);
}

// Round 14
// 161.895 us; speedup vs baseline: 1.8358x; 1.8358x over previous
//
#include <hip/hip_runtime.h>
#include <stdint.h>

#define NLAYERS 6
#define DD      128   // patch dim
#define CONDD   128
#define HID     256
#define DIN     192
#define TM      32    // tokens per block (4-wave blocks)
#define NTHR    256   // 4 waves
#define SA      72    // bufA row stride (elements): 64 + 8 pad
#define SB      264   // bufB/C row stride (elements): 256 + 8 pad

typedef __attribute__((ext_vector_type(4))) float f32x4;
typedef __attribute__((ext_vector_type(8))) short short8;
typedef __attribute__((ext_vector_type(2))) uint32_t u32x2;

// packed-weight geometry (16x16x32 bf16 MFMA B-fragments)
#define G1_KS 2
#define G2_KS 8
#define G3_KS 8
#define G1_FR (G1_KS*16)             // 32 frags
#define G2_FR (G2_KS*16)             // 128
#define G3_FR (G3_KS*8)              // 64
#define FR_L  (G1_FR+G2_FR+G3_FR)    // 224 frags / layer
#define EL_L  (FR_L*512)             // bf16 elems / layer
#define G2_OFF (G1_FR*512)
#define G3_OFF ((G1_FR+G2_FR)*512)

__device__ __forceinline__ short f2bf(float f) {   // fp32 -> bf16 (RNE), scalar
  uint32_t u = __builtin_bit_cast(uint32_t, f);
  u += 0x7fffu + ((u >> 16) & 1u);
  return (short)(u >> 16);
}
// HW packed convert: dst = {bf16(hi),bf16(lo)} in one instruction
__device__ __forceinline__ uint32_t cvtpk(float lo, float hi) {
  uint32_t r;
  asm("v_cvt_pk_bf16_f32 %0, %1, %2" : "=v"(r) : "v"(lo), "v"(hi));
  return r;
}
// κ₂⁻¹: phys position p in a κ₂-packed 256-wide h-buffer -> logical feature.
// Writer thread (nq,l15) stores its 4 outputs contiguously: phys 64nq+4*l15+idx
// holds logical 64nq+16*idx+l15  (one b64 write per (m2,r)).  HW-verified
// (absmax 4.0 in rounds 12/13).
__device__ __forceinline__ int kinv2(int p) {
  return (p & ~63) | ((p & 3) << 4) | ((p >> 2) & 15);
}

// Pack weights into bf16 MFMA B-fragment layout.
// W2/W3 K-rows permuted by κ₂⁻¹ (they consume κ₂-packed h1/h2).
// W3 output cols: frag (2g+h), lane-lo lv -> logical col c_l + 64h where
// c_l = (lay even) ? 16g+lv : 63-(16g+lv)  (label-flip coupling).
__global__ void prep_weights(const float* __restrict__ W1,
                             const float* __restrict__ W2,
                             const float* __restrict__ W3,
                             short* __restrict__ wp)
{
  int t = blockIdx.x * 256 + threadIdx.x;      // 6*224*64 = 86016 threads exactly
  int lay  = t / (FR_L * 64);
  int rem  = t - lay * (FR_L * 64);
  int frag = rem >> 6;
  int lane = rem & 63;
  const float* src;
  int N, f2, dstbase, nfr, perm;
  if (frag < G1_FR) {
    f2 = frag;                  src = W1 + (size_t)lay * DIN * HID; N = HID; dstbase = 0;      nfr = 16; perm = 0;
  } else if (frag < G1_FR + G2_FR) {
    f2 = frag - G1_FR;          src = W2 + (size_t)lay * HID * HID; N = HID; dstbase = G2_OFF; nfr = 16; perm = 1;
  } else {
    f2 = frag - (G1_FR + G2_FR);src = W3 + (size_t)lay * HID * DD;  N = DD;  dstbase = G3_OFF; nfr = 8;  perm = 2;
  }
  int ks = f2 / nfr, nf = f2 - ks * nfr;
  int lv = lane & 15;
  int n;
  if (perm == 2) {               // σ_l: pair (s,t) for the same logical col c_l
    int g = nf >> 1, h = nf & 1;
    int c = 16 * g + lv;
    if (lay & 1) c = 63 - c;
    n = c + 64 * h;
  } else {
    n = nf * 16 + lv;
  }
  int k0 = ks * 32 + (lane >> 4) * 8;
  short8 v;
#pragma unroll
  for (int j = 0; j < 8; ++j) {
    int k = perm ? kinv2(k0 + j) : (k0 + j);
    v[j] = f2bf(src[(size_t)k * N + n]);
  }
  *(short8*)(wp + (size_t)lay * EL_L + dstbase + ((size_t)f2 * 64 + lane) * 8) = v;
}

// c1[lay][batch][h] = cond[batch] @ W1[lay][64:192][h] + b1[lay][h]  (fp32, logical h)
__global__ void prep_c1(const float* __restrict__ cond, const float* __restrict__ W1,
                        const float* __restrict__ b1, float* __restrict__ c1)
{
  int lay = blockIdx.x >> 9;
  int b   = blockIdx.x & 511;
  int h   = threadIdx.x;
  const float* wb = W1 + (size_t)lay * DIN * HID + 64 * HID + h;
  const float* cb = cond + b * CONDD;
  float acc = b1[lay * HID + h];
#pragma unroll 4
  for (int c = 0; c < CONDD; ++c) acc = fmaf(cb[c], wb[(size_t)c * HID], acc);
  c1[((size_t)lay * 512 + b) * HID + h] = acc;
}

__global__ __launch_bounds__(NTHR, 4)
void flow_kernel(const float* __restrict__ x,
                 const float* __restrict__ c1g, const float* __restrict__ b2g,
                 const float* __restrict__ b3g, const short* __restrict__ wp,
                 float* __restrict__ outz, float* __restrict__ outld)
{
  // Round-11 structure (best verified: no cross-barrier register state,
  // exactly at the 128-VGPR budget) + κ₂ b64 epilogue writes.
  __shared__ alignas(16) short bufA[TM * SA];    // x1 bf16.           4.5KB
  __shared__ alignas(16) short bufB[TM * SB];    // h1 bf16 κ₂-packed. 16.5KB
  __shared__ alignas(16) short bufC[TM * SB];    // h2 bf16 κ₂-packed. 16.5KB
  __shared__ float red[4];

  const int tid  = threadIdx.x;
  const int wave = tid >> 6;                 // = col-quarter nq (0..3)
  const int lane = tid & 63;
  const int l15  = lane & 15;
  const int l4   = lane >> 4;
  const int nq   = wave;
  const int t0   = blockIdx.x * TM;
  const int batch = t0 >> 7;                 // 4 blocks per batch

  // z ownership: thread holds the dim-pair (c_l, 64+c_l) of its 8 rows,
  // c_0 = 16*nq + l15, c_{l+1} = 63 - c_l (label flip, no data motion).
  const int cB = 16 * nq + l15;
  const int rbase = 4 * l4;                  // rows rbase + 16*m2 + r (0..31)
  float zlo[8], zhi[8];
  {
    const float* xb = x + (size_t)t0 * DD;
#pragma unroll
    for (int m2 = 0; m2 < 2; ++m2)
#pragma unroll
      for (int r = 0; r < 4; ++r) {
        int j = m2 * 4 + r;
        int row = rbase + 16 * m2 + r;
        zlo[j] = xb[row * DD + cB];
        zhi[j] = xb[row * DD + 64 + cB];
      }
#pragma unroll
    for (int m2 = 0; m2 < 2; ++m2)           // stage x1 (bf16) for layer 0
#pragma unroll
      for (int r = 0; r < 4; ++r) {
        int row = rbase + 16 * m2 + r;
        bufA[row * SA + cB] = f2bf(zlo[m2 * 4 + r]);
      }
  }
  float ldsum = 0.f;
  __syncthreads();

#pragma unroll 1
  for (int lay = 0; lay < NLAYERS; ++lay) {
    const short* wl = wp + (size_t)lay * EL_L;
    const int cl = (lay & 1) ? (63 - cB) : cB;   // this layer's owned column

    // ---- GEMM1: [32x64] @ W1a[64x256], bias acc-init, relu -> bufB (κ₂) ----
    {
      const float* c1row = c1g + ((size_t)lay * 512 + batch) * HID;
      f32x4 acc[2][4];
#pragma unroll
      for (int nf = 0; nf < 4; ++nf) {       // acc init = bias (C/D col = lane&15)
        float b = c1row[64 * nq + 16 * nf + l15];
        f32x4 bi = {b, b, b, b};
        acc[0][nf] = bi; acc[1][nf] = bi;
      }
#pragma unroll 1
      for (int ks = 0; ks < G1_KS; ++ks) {
        short8 bb[4];
#pragma unroll
        for (int nf = 0; nf < 4; ++nf)
          bb[nf] = *(const short8*)(wl + (((ks * 16 + 4 * nq + nf) * 64 + lane) * 8));
#pragma unroll
        for (int m2 = 0; m2 < 2; ++m2) {
          int row = 16 * m2 + l15;
          short8 a = *(const short8*)(bufA + row * SA + ks * 32 + l4 * 8);
#pragma unroll
          for (int nf = 0; nf < 4; ++nf)
            acc[m2][nf] = __builtin_amdgcn_mfma_f32_16x16x32_bf16(a, bb[nf], acc[m2][nf], 0, 0, 0);
        }
      }
#pragma unroll
      for (int m2 = 0; m2 < 2; ++m2)         // κ₂-packed b64 writes
#pragma unroll
        for (int r = 0; r < 4; ++r) {
          int row = rbase + 16 * m2 + r;
          u32x2 val = {cvtpk(fmaxf(acc[m2][0][r], 0.f), fmaxf(acc[m2][1][r], 0.f)),
                       cvtpk(fmaxf(acc[m2][2][r], 0.f), fmaxf(acc[m2][3][r], 0.f))};
          *(u32x2*)(bufB + row * SB + 64 * nq + 4 * l15) = val;
        }
    }
    __syncthreads();                         // B1: h1 ready

    // ---- GEMM2: bufB(h1) @ W2, bias-init, relu -> bufC (κ₂) ----
    {
      const short* wg = wl + G2_OFF;
      f32x4 acc[2][4];
#pragma unroll
      for (int nf = 0; nf < 4; ++nf) {
        float b = b2g[lay * HID + 64 * nq + 16 * nf + l15];
        f32x4 bi = {b, b, b, b};
        acc[0][nf] = bi; acc[1][nf] = bi;
      }
#pragma unroll 2
      for (int ks = 0; ks < G2_KS; ++ks) {
        short8 bb[4];
#pragma unroll
        for (int nf = 0; nf < 4; ++nf)
          bb[nf] = *(const short8*)(wg + (((ks * 16 + 4 * nq + nf) * 64 + lane) * 8));
#pragma unroll
        for (int m2 = 0; m2 < 2; ++m2) {
          int row = 16 * m2 + l15;
          short8 a = *(const short8*)(bufB + row * SB + ks * 32 + l4 * 8);
#pragma unroll
          for (int nf = 0; nf < 4; ++nf)
            acc[m2][nf] = __builtin_amdgcn_mfma_f32_16x16x32_bf16(a, bb[nf], acc[m2][nf], 0, 0, 0);
        }
      }
#pragma unroll
      for (int m2 = 0; m2 < 2; ++m2)         // κ₂-packed b64 writes
#pragma unroll
        for (int r = 0; r < 4; ++r) {
          int row = rbase + 16 * m2 + r;
          u32x2 val = {cvtpk(fmaxf(acc[m2][0][r], 0.f), fmaxf(acc[m2][1][r], 0.f)),
                       cvtpk(fmaxf(acc[m2][2][r], 0.f), fmaxf(acc[m2][3][r], 0.f))};
          *(u32x2*)(bufC + row * SB + 64 * nq + 4 * l15) = val;
        }
    }
    __syncthreads();                         // B2: h2 ready

    // ---- GEMM3 + coupling in registers (σ_l-paired s,t; label flip) ----
    {
      f32x4 acc3[2][2];
      {
        float bs = b3g[lay * DD + cl];
        float bt = b3g[lay * DD + 64 + cl];
        f32x4 bsi = {bs, bs, bs, bs}, bti = {bt, bt, bt, bt};
        acc3[0][0] = bsi; acc3[1][0] = bsi;
        acc3[0][1] = bti; acc3[1][1] = bti;
      }
#pragma unroll 2
      for (int ks = 0; ks < G3_KS; ++ks) {
        short8 bb[2];
#pragma unroll
        for (int nf = 0; nf < 2; ++nf)
          bb[nf] = *(const short8*)(wl + G3_OFF + (((ks * 8 + 2 * nq + nf) * 64 + lane) * 8));
#pragma unroll
        for (int m2 = 0; m2 < 2; ++m2) {
          int row = 16 * m2 + l15;
          short8 a = *(const short8*)(bufC + row * SB + ks * 32 + l4 * 8);
          acc3[m2][0] = __builtin_amdgcn_mfma_f32_16x16x32_bf16(a, bb[0], acc3[m2][0], 0, 0, 0);
          acc3[m2][1] = __builtin_amdgcn_mfma_f32_16x16x32_bf16(a, bb[1], acc3[m2][1], 0, 0, 0);
        }
      }
      // coupling: y2 = x2*exp(s)+t.  Label flip c->63-c: new (zlo,zhi) =
      // (y2, old x1) with NO cross-lane exchange.
#pragma unroll
      for (int m2 = 0; m2 < 2; ++m2)
#pragma unroll
        for (int r = 0; r < 4; ++r) {
          int j = m2 * 4 + r;
          float sr = fminf(fmaxf(acc3[m2][0][r], -8.f), 8.f);
          float tt = acc3[m2][1][r];
          float e2 = __expf(2.f * sr);
          float s  = 0.5f * (e2 - 1.f) / (e2 + 1.f);   // 0.5*tanh(sr)
          ldsum += s;
          float y2 = fmaf(zhi[j], __expf(s), tt);
          zhi[j] = zlo[j];                   // new x2 half = old x1
          zlo[j] = y2;                       // new x1 half = y2
        }
      if (lay < NLAYERS - 1) {
        int cn = 63 - cl;                    // next layer's owned column
#pragma unroll
        for (int m2 = 0; m2 < 2; ++m2)       // stage next layer's x1 (bf16)
#pragma unroll
          for (int r = 0; r < 4; ++r) {
            int row = rbase + 16 * m2 + r;
            bufA[row * SA + cn] = f2bf(zlo[m2 * 4 + r]);
          }
        __syncthreads();                     // B3: bufA staged; h2 reads done
      }
    }
  }

  { // store z (c_6 = cB after 6 label flips)
    float* ob = outz + (size_t)t0 * DD;
#pragma unroll
    for (int m2 = 0; m2 < 2; ++m2)
#pragma unroll
      for (int r = 0; r < 4; ++r) {
        int j = m2 * 4 + r;
        int row = rbase + 16 * m2 + r;
        ob[row * DD + cB]      = zlo[j];
        ob[row * DD + 64 + cB] = zhi[j];
      }
  }
  // logdet: wave shuffle-reduce -> block -> one atomic (4 blocks/batch, commutative)
#pragma unroll
  for (int off = 32; off > 0; off >>= 1) ldsum += __shfl_down(ldsum, off);
  if (lane == 0) red[wave] = ldsum;
  __syncthreads();
  if (tid == 0) {
    float s = red[0] + red[1] + red[2] + red[3];
    atomicAdd(&outld[batch], s);
  }
}

extern "C" void kernel_launch(void* const* d_in, const int* in_sizes, int n_in,
                              void* d_out, int out_size, void* d_ws, size_t ws_size,
                              hipStream_t stream)
{
  (void)in_sizes; (void)n_in; (void)out_size; (void)ws_size;
  const float* x   = (const float*)d_in[0];
  const float* cnd = (const float*)d_in[1];
  const float* W1  = (const float*)d_in[2];
  const float* b1  = (const float*)d_in[3];
  const float* W2  = (const float*)d_in[4];
  const float* b2  = (const float*)d_in[5];
  const float* W3  = (const float*)d_in[6];
  const float* b3  = (const float*)d_in[7];
  float* outz  = (float*)d_out;
  float* outld = outz + (size_t)512 * 128 * 128;
  short* wp = (short*)d_ws;                            // 1.38 MB packed bf16 weights
  float* c1 = (float*)((char*)d_ws + (2u << 20));      // 3.1 MB fp32 cond-bias

  hipMemsetAsync(outld, 0, 512 * sizeof(float), stream);
  prep_weights<<<336, 256, 0, stream>>>(W1, W2, W3, wp);
  prep_c1<<<6 * 512, 256, 0, stream>>>(cnd, W1, b1, c1);
  flow_kernel<<<2048, NTHR, 0, stream>>>(x, c1, b2, b3, wp, outz, outld);
}

// Round 15
// 160.351 us; speedup vs baseline: 1.8535x; 1.0096x over previous
//
#include <hip/hip_runtime.h>
#include <stdint.h>

#define NLAYERS 6
#define DD      128   // patch dim
#define CONDD   128
#define HID     256
#define DIN     192
#define TM      32    // tokens per block (4-wave blocks)
#define NTHR    256   // 4 waves
#define SA      72    // bufA row stride (elements): 64 + 8 pad
#define SB      264   // bufB/C row stride (elements): 256 + 8 pad

typedef __attribute__((ext_vector_type(4))) float f32x4;
typedef __attribute__((ext_vector_type(8))) short short8;

// packed-weight geometry (16x16x32 bf16 MFMA B-fragments)
#define G1_KS 2
#define G2_KS 8
#define G3_KS 8
#define G1_FR (G1_KS*16)             // 32 frags
#define G2_FR (G2_KS*16)             // 128
#define G3_FR (G3_KS*8)              // 64
#define FR_L  (G1_FR+G2_FR+G3_FR)    // 224 frags / layer
#define EL_L  (FR_L*512)             // bf16 elems / layer
#define G2_OFF (G1_FR*512)
#define G3_OFF ((G1_FR+G2_FR)*512)

__device__ __forceinline__ short f2bf(float f) {   // fp32 -> bf16 (RNE), scalar
  uint32_t u = __builtin_bit_cast(uint32_t, f);
  u += 0x7fffu + ((u >> 16) & 1u);
  return (short)(u >> 16);
}
// HW packed convert: dst = {bf16(hi),bf16(lo)} in one instruction
__device__ __forceinline__ uint32_t cvtpk(float lo, float hi) {
  uint32_t r;
  asm("v_cvt_pk_bf16_f32 %0, %1, %2" : "=v"(r) : "v"(lo), "v"(hi));
  return r;
}
// κ⁻¹: phys position p in a κ-packed 256-wide h-buffer -> logical feature index
__device__ __forceinline__ int kinv(int p) {
  return (p & ~63) | (p & 32) | ((p & 1) << 4) | ((p >> 1) & 15);
}

// Pack weights into bf16 MFMA B-fragment layout.
// W2/W3 K-rows permuted by κ⁻¹ (they consume κ-packed h1/h2).
// W3 output cols: frag (2g+h), lane-lo lv -> logical col c_l + 64h where
// c_l = (lay even) ? 16g+lv : 63-(16g+lv)  (label-flip coupling).
__global__ void prep_weights(const float* __restrict__ W1,
                             const float* __restrict__ W2,
                             const float* __restrict__ W3,
                             short* __restrict__ wp)
{
  int t = blockIdx.x * 256 + threadIdx.x;      // 6*224*64 = 86016 threads exactly
  int lay  = t / (FR_L * 64);
  int rem  = t - lay * (FR_L * 64);
  int frag = rem >> 6;
  int lane = rem & 63;
  const float* src;
  int N, f2, dstbase, nfr, perm;
  if (frag < G1_FR) {
    f2 = frag;                  src = W1 + (size_t)lay * DIN * HID; N = HID; dstbase = 0;      nfr = 16; perm = 0;
  } else if (frag < G1_FR + G2_FR) {
    f2 = frag - G1_FR;          src = W2 + (size_t)lay * HID * HID; N = HID; dstbase = G2_OFF; nfr = 16; perm = 1;
  } else {
    f2 = frag - (G1_FR + G2_FR);src = W3 + (size_t)lay * HID * DD;  N = DD;  dstbase = G3_OFF; nfr = 8;  perm = 2;
  }
  int ks = f2 / nfr, nf = f2 - ks * nfr;
  int lv = lane & 15;
  int n;
  if (perm == 2) {               // σ_l: pair (s,t) for the same logical col c_l
    int g = nf >> 1, h = nf & 1;
    int c = 16 * g + lv;
    if (lay & 1) c = 63 - c;
    n = c + 64 * h;
  } else {
    n = nf * 16 + lv;
  }
  int k0 = ks * 32 + (lane >> 4) * 8;
  short8 v;
#pragma unroll
  for (int j = 0; j < 8; ++j) {
    int k = perm ? kinv(k0 + j) : (k0 + j);
    v[j] = f2bf(src[(size_t)k * N + n]);
  }
  *(short8*)(wp + (size_t)lay * EL_L + dstbase + ((size_t)f2 * 64 + lane) * 8) = v;
}

// c1[lay][batch][h] = cond[batch] @ W1[lay][64:192][h] + b1[lay][h]  (fp32, logical h)
__global__ void prep_c1(const float* __restrict__ cond, const float* __restrict__ W1,
                        const float* __restrict__ b1, float* __restrict__ c1)
{
  int lay = blockIdx.x >> 9;
  int b   = blockIdx.x & 511;
  int h   = threadIdx.x;
  const float* wb = W1 + (size_t)lay * DIN * HID + 64 * HID + h;
  const float* cb = cond + b * CONDD;
  float acc = b1[lay * HID + h];
#pragma unroll 4
  for (int c = 0; c < CONDD; ++c) acc = fmaf(cb[c], wb[(size_t)c * HID], acc);
  c1[((size_t)lay * 512 + b) * HID + h] = acc;
}

__global__ __launch_bounds__(NTHR, 4)
void flow_kernel(const float* __restrict__ x,
                 const float* __restrict__ c1g, const float* __restrict__ b2g,
                 const float* __restrict__ b3g, const short* __restrict__ wp,
                 float* __restrict__ outz, float* __restrict__ outld)
{
  // R11 structure (best verified: 139.5us, zero spill, 4 independent
  // barrier domains/CU) + T5 s_setprio around MFMA bursts.
  __shared__ alignas(16) short bufA[TM * SA];    // x1 bf16.          4.5KB
  __shared__ alignas(16) short bufB[TM * SB];    // h1 bf16 κ-packed. 16.5KB
  __shared__ alignas(16) short bufC[TM * SB];    // h2 bf16 κ-packed. 16.5KB
  __shared__ float red[4];

  const int tid  = threadIdx.x;
  const int wave = tid >> 6;                 // = col-quarter nq (0..3)
  const int lane = tid & 63;
  const int l15  = lane & 15;
  const int l4   = lane >> 4;
  const int nq   = wave;
  const int t0   = blockIdx.x * TM;
  const int batch = t0 >> 7;                 // 4 blocks per batch

  // z ownership: thread holds the dim-pair (c_l, 64+c_l) of its 8 rows,
  // c_0 = 16*nq + l15, c_{l+1} = 63 - c_l (label flip, no data motion).
  const int cB = 16 * nq + l15;
  const int rbase = 4 * l4;                  // rows rbase + 16*m2 + r (0..31)
  float zlo[8], zhi[8];
  {
    const float* xb = x + (size_t)t0 * DD;
#pragma unroll
    for (int m2 = 0; m2 < 2; ++m2)
#pragma unroll
      for (int r = 0; r < 4; ++r) {
        int j = m2 * 4 + r;
        int row = rbase + 16 * m2 + r;
        zlo[j] = xb[row * DD + cB];
        zhi[j] = xb[row * DD + 64 + cB];
      }
#pragma unroll
    for (int m2 = 0; m2 < 2; ++m2)           // stage x1 (bf16) for layer 0
#pragma unroll
      for (int r = 0; r < 4; ++r) {
        int row = rbase + 16 * m2 + r;
        bufA[row * SA + cB] = f2bf(zlo[m2 * 4 + r]);
      }
  }
  float ldsum = 0.f;
  __syncthreads();

#pragma unroll 1
  for (int lay = 0; lay < NLAYERS; ++lay) {
    const short* wl = wp + (size_t)lay * EL_L;
    const int cl = (lay & 1) ? (63 - cB) : cB;   // this layer's owned column

    // ---- GEMM1: [32x64] @ W1a[64x256], bias acc-init, relu -> bufB (κ) ----
    {
      const float* c1row = c1g + ((size_t)lay * 512 + batch) * HID;
      f32x4 acc[2][4];
#pragma unroll
      for (int nf = 0; nf < 4; ++nf) {       // acc init = bias (C/D col = lane&15)
        float b = c1row[64 * nq + 16 * nf + l15];
        f32x4 bi = {b, b, b, b};
        acc[0][nf] = bi; acc[1][nf] = bi;
      }
#pragma unroll 1
      for (int ks = 0; ks < G1_KS; ++ks) {
        short8 bb[4];
#pragma unroll
        for (int nf = 0; nf < 4; ++nf)
          bb[nf] = *(const short8*)(wl + (((ks * 16 + 4 * nq + nf) * 64 + lane) * 8));
        __builtin_amdgcn_s_setprio(1);       // T5: prioritize MFMA burst
#pragma unroll
        for (int m2 = 0; m2 < 2; ++m2) {
          int row = 16 * m2 + l15;
          short8 a = *(const short8*)(bufA + row * SA + ks * 32 + l4 * 8);
#pragma unroll
          for (int nf = 0; nf < 4; ++nf)
            acc[m2][nf] = __builtin_amdgcn_mfma_f32_16x16x32_bf16(a, bb[nf], acc[m2][nf], 0, 0, 0);
        }
        __builtin_amdgcn_s_setprio(0);
      }
#pragma unroll
      for (int h = 0; h < 2; ++h)
#pragma unroll
        for (int m2 = 0; m2 < 2; ++m2)
#pragma unroll
          for (int r = 0; r < 4; ++r) {
            int row = rbase + 16 * m2 + r;
            float v0 = fmaxf(acc[m2][2 * h][r], 0.f);
            float v1 = fmaxf(acc[m2][2 * h + 1][r], 0.f);
            *(uint32_t*)(bufB + row * SB + 64 * nq + 32 * h + 2 * l15) = cvtpk(v0, v1);
          }
    }
    __syncthreads();                         // B1: h1 ready

    // ---- GEMM2: bufB(h1) @ W2, bias-init, relu -> bufC (κ) ----
    {
      const short* wg = wl + G2_OFF;
      f32x4 acc[2][4];
#pragma unroll
      for (int nf = 0; nf < 4; ++nf) {
        float b = b2g[lay * HID + 64 * nq + 16 * nf + l15];
        f32x4 bi = {b, b, b, b};
        acc[0][nf] = bi; acc[1][nf] = bi;
      }
#pragma unroll 2
      for (int ks = 0; ks < G2_KS; ++ks) {
        short8 bb[4];
#pragma unroll
        for (int nf = 0; nf < 4; ++nf)
          bb[nf] = *(const short8*)(wg + (((ks * 16 + 4 * nq + nf) * 64 + lane) * 8));
        __builtin_amdgcn_s_setprio(1);       // T5
#pragma unroll
        for (int m2 = 0; m2 < 2; ++m2) {
          int row = 16 * m2 + l15;
          short8 a = *(const short8*)(bufB + row * SB + ks * 32 + l4 * 8);
#pragma unroll
          for (int nf = 0; nf < 4; ++nf)
            acc[m2][nf] = __builtin_amdgcn_mfma_f32_16x16x32_bf16(a, bb[nf], acc[m2][nf], 0, 0, 0);
        }
        __builtin_amdgcn_s_setprio(0);
      }
#pragma unroll
      for (int h = 0; h < 2; ++h)
#pragma unroll
        for (int m2 = 0; m2 < 2; ++m2)
#pragma unroll
          for (int r = 0; r < 4; ++r) {
            int row = rbase + 16 * m2 + r;
            float v0 = fmaxf(acc[m2][2 * h][r], 0.f);
            float v1 = fmaxf(acc[m2][2 * h + 1][r], 0.f);
            *(uint32_t*)(bufC + row * SB + 64 * nq + 32 * h + 2 * l15) = cvtpk(v0, v1);
          }
    }
    __syncthreads();                         // B2: h2 ready

    // ---- GEMM3 + coupling in registers (σ_l-paired s,t; label flip) ----
    {
      f32x4 acc3[2][2];
      {
        float bs = b3g[lay * DD + cl];
        float bt = b3g[lay * DD + 64 + cl];
        f32x4 bsi = {bs, bs, bs, bs}, bti = {bt, bt, bt, bt};
        acc3[0][0] = bsi; acc3[1][0] = bsi;
        acc3[0][1] = bti; acc3[1][1] = bti;
      }
#pragma unroll 2
      for (int ks = 0; ks < G3_KS; ++ks) {
        short8 bb[2];
#pragma unroll
        for (int nf = 0; nf < 2; ++nf)
          bb[nf] = *(const short8*)(wl + G3_OFF + (((ks * 8 + 2 * nq + nf) * 64 + lane) * 8));
        __builtin_amdgcn_s_setprio(1);       // T5
#pragma unroll
        for (int m2 = 0; m2 < 2; ++m2) {
          int row = 16 * m2 + l15;
          short8 a = *(const short8*)(bufC + row * SB + ks * 32 + l4 * 8);
          acc3[m2][0] = __builtin_amdgcn_mfma_f32_16x16x32_bf16(a, bb[0], acc3[m2][0], 0, 0, 0);
          acc3[m2][1] = __builtin_amdgcn_mfma_f32_16x16x32_bf16(a, bb[1], acc3[m2][1], 0, 0, 0);
        }
        __builtin_amdgcn_s_setprio(0);
      }
      // coupling: y2 = x2*exp(s)+t.  Label flip c->63-c: new (zlo,zhi) =
      // (y2, old x1) with NO cross-lane exchange.
#pragma unroll
      for (int m2 = 0; m2 < 2; ++m2)
#pragma unroll
        for (int r = 0; r < 4; ++r) {
          int j = m2 * 4 + r;
          float sr = fminf(fmaxf(acc3[m2][0][r], -8.f), 8.f);
          float tt = acc3[m2][1][r];
          float e2 = __expf(2.f * sr);
          float s  = 0.5f * (e2 - 1.f) / (e2 + 1.f);   // 0.5*tanh(sr)
          ldsum += s;
          float y2 = fmaf(zhi[j], __expf(s), tt);
          zhi[j] = zlo[j];                   // new x2 half = old x1
          zlo[j] = y2;                       // new x1 half = y2
        }
      if (lay < NLAYERS - 1) {
        int cn = 63 - cl;                    // next layer's owned column
#pragma unroll
        for (int m2 = 0; m2 < 2; ++m2)       // stage next layer's x1 (bf16)
#pragma unroll
          for (int r = 0; r < 4; ++r) {
            int row = rbase + 16 * m2 + r;
            bufA[row * SA + cn] = f2bf(zlo[m2 * 4 + r]);
          }
        __syncthreads();                     // B3: bufA staged; h2 reads done
      }
    }
  }

  { // store z (c_6 = cB after 6 label flips)
    float* ob = outz + (size_t)t0 * DD;
#pragma unroll
    for (int m2 = 0; m2 < 2; ++m2)
#pragma unroll
      for (int r = 0; r < 4; ++r) {
        int j = m2 * 4 + r;
        int row = rbase + 16 * m2 + r;
        ob[row * DD + cB]      = zlo[j];
        ob[row * DD + 64 + cB] = zhi[j];
      }
  }
  // logdet: wave shuffle-reduce -> block -> one atomic (4 blocks/batch, commutative)
#pragma unroll
  for (int off = 32; off > 0; off >>= 1) ldsum += __shfl_down(ldsum, off);
  if (lane == 0) red[wave] = ldsum;
  __syncthreads();
  if (tid == 0) {
    float s = red[0] + red[1] + red[2] + red[3];
    atomicAdd(&outld[batch], s);
  }
}

extern "C" void kernel_launch(void* const* d_in, const int* in_sizes, int n_in,
                              void* d_out, int out_size, void* d_ws, size_t ws_size,
                              hipStream_t stream)
{
  (void)in_sizes; (void)n_in; (void)out_size; (void)ws_size;
  const float* x   = (const float*)d_in[0];
  const float* cnd = (const float*)d_in[1];
  const float* W1  = (const float*)d_in[2];
  const float* b1  = (const float*)d_in[3];
  const float* W2  = (const float*)d_in[4];
  const float* b2  = (const float*)d_in[5];
  const float* W3  = (const float*)d_in[6];
  const float* b3  = (const float*)d_in[7];
  float* outz  = (float*)d_out;
  float* outld = outz + (size_t)512 * 128 * 128;
  short* wp = (short*)d_ws;                            // 1.38 MB packed bf16 weights
  float* c1 = (float*)((char*)d_ws + (2u << 20));      // 3.1 MB fp32 cond-bias

  hipMemsetAsync(outld, 0, 512 * sizeof(float), stream);
  prep_weights<<<336, 256, 0, stream>>>(W1, W2, W3, wp);
  prep_c1<<<6 * 512, 256, 0, stream>>>(cnd, W1, b1, c1);
  flow_kernel<<<2048, NTHR, 0, stream>>>(x, c1, b2, b3, wp, outz, outld);
}

// Round 16
// 159.916 us; speedup vs baseline: 1.8586x; 1.0027x over previous
//
#include <hip/hip_runtime.h>
#include <stdint.h>

#define NLAYERS 6
#define DD      128   // patch dim
#define CONDD   128
#define HID     256
#define DIN     192
#define TM      32    // tokens per block (4-wave blocks)
#define NTHR    256   // 4 waves
#define SA      72    // bufA row stride (elements): 64 + 8 pad
#define SB      264   // bufB/C row stride (elements): 256 + 8 pad

typedef __attribute__((ext_vector_type(4))) float f32x4;
typedef __attribute__((ext_vector_type(8))) short short8;

// packed-weight geometry (16x16x32 bf16 MFMA B-fragments)
#define G1_KS 2
#define G2_KS 8
#define G3_KS 8
#define G1_FR (G1_KS*16)             // 32 frags
#define G2_FR (G2_KS*16)             // 128
#define G3_FR (G3_KS*8)              // 64
#define FR_L  (G1_FR+G2_FR+G3_FR)    // 224 frags / layer
#define EL_L  (FR_L*512)             // bf16 elems / layer
#define G2_OFF (G1_FR*512)
#define G3_OFF ((G1_FR+G2_FR)*512)

__device__ __forceinline__ short f2bf(float f) {   // fp32 -> bf16 (RNE), scalar
  uint32_t u = __builtin_bit_cast(uint32_t, f);
  u += 0x7fffu + ((u >> 16) & 1u);
  return (short)(u >> 16);
}
// HW packed convert: dst = {bf16(hi),bf16(lo)} in one instruction
__device__ __forceinline__ uint32_t cvtpk(float lo, float hi) {
  uint32_t r;
  asm("v_cvt_pk_bf16_f32 %0, %1, %2" : "=v"(r) : "v"(lo), "v"(hi));
  return r;
}
// κ⁻¹: phys position p in a κ-packed 256-wide h-buffer -> logical feature index
__device__ __forceinline__ int kinv(int p) {
  return (p & ~63) | (p & 32) | ((p & 1) << 4) | ((p >> 1) & 15);
}

// Pack weights into bf16 MFMA B-fragment layout.
// W2/W3 K-rows permuted by κ⁻¹ (they consume κ-packed h1/h2).
// W3 output cols: frag (2g+h), lane-lo lv -> logical col c_l + 64h where
// c_l = (lay even) ? 16g+lv : 63-(16g+lv)  (label-flip coupling).
__global__ void prep_weights(const float* __restrict__ W1,
                             const float* __restrict__ W2,
                             const float* __restrict__ W3,
                             short* __restrict__ wp)
{
  int t = blockIdx.x * 256 + threadIdx.x;      // 6*224*64 = 86016 threads exactly
  int lay  = t / (FR_L * 64);
  int rem  = t - lay * (FR_L * 64);
  int frag = rem >> 6;
  int lane = rem & 63;
  const float* src;
  int N, f2, dstbase, nfr, perm;
  if (frag < G1_FR) {
    f2 = frag;                  src = W1 + (size_t)lay * DIN * HID; N = HID; dstbase = 0;      nfr = 16; perm = 0;
  } else if (frag < G1_FR + G2_FR) {
    f2 = frag - G1_FR;          src = W2 + (size_t)lay * HID * HID; N = HID; dstbase = G2_OFF; nfr = 16; perm = 1;
  } else {
    f2 = frag - (G1_FR + G2_FR);src = W3 + (size_t)lay * HID * DD;  N = DD;  dstbase = G3_OFF; nfr = 8;  perm = 2;
  }
  int ks = f2 / nfr, nf = f2 - ks * nfr;
  int lv = lane & 15;
  int n;
  if (perm == 2) {               // σ_l: pair (s,t) for the same logical col c_l
    int g = nf >> 1, h = nf & 1;
    int c = 16 * g + lv;
    if (lay & 1) c = 63 - c;
    n = c + 64 * h;
  } else {
    n = nf * 16 + lv;
  }
  int k0 = ks * 32 + (lane >> 4) * 8;
  short8 v;
#pragma unroll
  for (int j = 0; j < 8; ++j) {
    int k = perm ? kinv(k0 + j) : (k0 + j);
    v[j] = f2bf(src[(size_t)k * N + n]);
  }
  *(short8*)(wp + (size_t)lay * EL_L + dstbase + ((size_t)f2 * 64 + lane) * 8) = v;
}

// c1[lay][batch][h] = cond[batch] @ W1[lay][64:192][h] + b1[lay][h]  (fp32, logical h)
__global__ void prep_c1(const float* __restrict__ cond, const float* __restrict__ W1,
                        const float* __restrict__ b1, float* __restrict__ c1)
{
  int lay = blockIdx.x >> 9;
  int b   = blockIdx.x & 511;
  int h   = threadIdx.x;
  const float* wb = W1 + (size_t)lay * DIN * HID + 64 * HID + h;
  const float* cb = cond + b * CONDD;
  float acc = b1[lay * HID + h];
#pragma unroll 4
  for (int c = 0; c < CONDD; ++c) acc = fmaf(cb[c], wb[(size_t)c * HID], acc);
  c1[((size_t)lay * 512 + b) * HID + h] = acc;
}

__global__ __launch_bounds__(NTHR, 4)
void flow_kernel(const float* __restrict__ x,
                 const float* __restrict__ c1g, const float* __restrict__ b2g,
                 const float* __restrict__ b3g, const short* __restrict__ wp,
                 float* __restrict__ outz, float* __restrict__ outld)
{
  // Best verified configuration (R11): TM=32 / 4-wave blocks, 38.9KB LDS
  // -> 4 independent barrier domains/CU at the 128-VGPR/4-wave budget,
  // row-padded LDS (immediate-offset addressing, no XOR math), bias folded
  // into MFMA accumulator init, label-flip coupling (zero cross-lane traffic).
  __shared__ alignas(16) short bufA[TM * SA];    // x1 bf16.          4.5KB
  __shared__ alignas(16) short bufB[TM * SB];    // h1 bf16 κ-packed. 16.5KB
  __shared__ alignas(16) short bufC[TM * SB];    // h2 bf16 κ-packed. 16.5KB
  __shared__ float red[4];

  const int tid  = threadIdx.x;
  const int wave = tid >> 6;                 // = col-quarter nq (0..3)
  const int lane = tid & 63;
  const int l15  = lane & 15;
  const int l4   = lane >> 4;
  const int nq   = wave;
  const int t0   = blockIdx.x * TM;
  const int batch = t0 >> 7;                 // 4 blocks per batch

  // z ownership: thread holds the dim-pair (c_l, 64+c_l) of its 8 rows,
  // c_0 = 16*nq + l15, c_{l+1} = 63 - c_l (label flip, no data motion).
  const int cB = 16 * nq + l15;
  const int rbase = 4 * l4;                  // rows rbase + 16*m2 + r (0..31)
  float zlo[8], zhi[8];
  {
    const float* xb = x + (size_t)t0 * DD;
#pragma unroll
    for (int m2 = 0; m2 < 2; ++m2)
#pragma unroll
      for (int r = 0; r < 4; ++r) {
        int j = m2 * 4 + r;
        int row = rbase + 16 * m2 + r;
        zlo[j] = xb[row * DD + cB];
        zhi[j] = xb[row * DD + 64 + cB];
      }
#pragma unroll
    for (int m2 = 0; m2 < 2; ++m2)           // stage x1 (bf16) for layer 0
#pragma unroll
      for (int r = 0; r < 4; ++r) {
        int row = rbase + 16 * m2 + r;
        bufA[row * SA + cB] = f2bf(zlo[m2 * 4 + r]);
      }
  }
  float ldsum = 0.f;
  __syncthreads();

#pragma unroll 1
  for (int lay = 0; lay < NLAYERS; ++lay) {
    const short* wl = wp + (size_t)lay * EL_L;
    const int cl = (lay & 1) ? (63 - cB) : cB;   // this layer's owned column

    // ---- GEMM1: [32x64] @ W1a[64x256], bias acc-init, relu -> bufB (κ) ----
    {
      const float* c1row = c1g + ((size_t)lay * 512 + batch) * HID;
      f32x4 acc[2][4];
#pragma unroll
      for (int nf = 0; nf < 4; ++nf) {       // acc init = bias (C/D col = lane&15)
        float b = c1row[64 * nq + 16 * nf + l15];
        f32x4 bi = {b, b, b, b};
        acc[0][nf] = bi; acc[1][nf] = bi;
      }
#pragma unroll 1
      for (int ks = 0; ks < G1_KS; ++ks) {
        short8 bb[4];
#pragma unroll
        for (int nf = 0; nf < 4; ++nf)
          bb[nf] = *(const short8*)(wl + (((ks * 16 + 4 * nq + nf) * 64 + lane) * 8));
#pragma unroll
        for (int m2 = 0; m2 < 2; ++m2) {
          int row = 16 * m2 + l15;
          short8 a = *(const short8*)(bufA + row * SA + ks * 32 + l4 * 8);
#pragma unroll
          for (int nf = 0; nf < 4; ++nf)
            acc[m2][nf] = __builtin_amdgcn_mfma_f32_16x16x32_bf16(a, bb[nf], acc[m2][nf], 0, 0, 0);
        }
      }
#pragma unroll
      for (int h = 0; h < 2; ++h)
#pragma unroll
        for (int m2 = 0; m2 < 2; ++m2)
#pragma unroll
          for (int r = 0; r < 4; ++r) {
            int row = rbase + 16 * m2 + r;
            float v0 = fmaxf(acc[m2][2 * h][r], 0.f);
            float v1 = fmaxf(acc[m2][2 * h + 1][r], 0.f);
            *(uint32_t*)(bufB + row * SB + 64 * nq + 32 * h + 2 * l15) = cvtpk(v0, v1);
          }
    }
    __syncthreads();                         // B1: h1 ready

    // ---- GEMM2: bufB(h1) @ W2, bias-init, relu -> bufC (κ) ----
    {
      const short* wg = wl + G2_OFF;
      f32x4 acc[2][4];
#pragma unroll
      for (int nf = 0; nf < 4; ++nf) {
        float b = b2g[lay * HID + 64 * nq + 16 * nf + l15];
        f32x4 bi = {b, b, b, b};
        acc[0][nf] = bi; acc[1][nf] = bi;
      }
#pragma unroll 2
      for (int ks = 0; ks < G2_KS; ++ks) {
        short8 bb[4];
#pragma unroll
        for (int nf = 0; nf < 4; ++nf)
          bb[nf] = *(const short8*)(wg + (((ks * 16 + 4 * nq + nf) * 64 + lane) * 8));
#pragma unroll
        for (int m2 = 0; m2 < 2; ++m2) {
          int row = 16 * m2 + l15;
          short8 a = *(const short8*)(bufB + row * SB + ks * 32 + l4 * 8);
#pragma unroll
          for (int nf = 0; nf < 4; ++nf)
            acc[m2][nf] = __builtin_amdgcn_mfma_f32_16x16x32_bf16(a, bb[nf], acc[m2][nf], 0, 0, 0);
        }
      }
#pragma unroll
      for (int h = 0; h < 2; ++h)
#pragma unroll
        for (int m2 = 0; m2 < 2; ++m2)
#pragma unroll
          for (int r = 0; r < 4; ++r) {
            int row = rbase + 16 * m2 + r;
            float v0 = fmaxf(acc[m2][2 * h][r], 0.f);
            float v1 = fmaxf(acc[m2][2 * h + 1][r], 0.f);
            *(uint32_t*)(bufC + row * SB + 64 * nq + 32 * h + 2 * l15) = cvtpk(v0, v1);
          }
    }
    __syncthreads();                         // B2: h2 ready

    // ---- GEMM3 + coupling in registers (σ_l-paired s,t; label flip) ----
    {
      f32x4 acc3[2][2];
      {
        float bs = b3g[lay * DD + cl];
        float bt = b3g[lay * DD + 64 + cl];
        f32x4 bsi = {bs, bs, bs, bs}, bti = {bt, bt, bt, bt};
        acc3[0][0] = bsi; acc3[1][0] = bsi;
        acc3[0][1] = bti; acc3[1][1] = bti;
      }
#pragma unroll 2
      for (int ks = 0; ks < G3_KS; ++ks) {
        short8 bb[2];
#pragma unroll
        for (int nf = 0; nf < 2; ++nf)
          bb[nf] = *(const short8*)(wl + G3_OFF + (((ks * 8 + 2 * nq + nf) * 64 + lane) * 8));
#pragma unroll
        for (int m2 = 0; m2 < 2; ++m2) {
          int row = 16 * m2 + l15;
          short8 a = *(const short8*)(bufC + row * SB + ks * 32 + l4 * 8);
          acc3[m2][0] = __builtin_amdgcn_mfma_f32_16x16x32_bf16(a, bb[0], acc3[m2][0], 0, 0, 0);
          acc3[m2][1] = __builtin_amdgcn_mfma_f32_16x16x32_bf16(a, bb[1], acc3[m2][1], 0, 0, 0);
        }
      }
      // coupling: y2 = x2*exp(s)+t.  Label flip c->63-c: new (zlo,zhi) =
      // (y2, old x1) with NO cross-lane exchange.
#pragma unroll
      for (int m2 = 0; m2 < 2; ++m2)
#pragma unroll
        for (int r = 0; r < 4; ++r) {
          int j = m2 * 4 + r;
          float sr = fminf(fmaxf(acc3[m2][0][r], -8.f), 8.f);
          float tt = acc3[m2][1][r];
          float e2 = __expf(2.f * sr);
          float s  = 0.5f * (e2 - 1.f) / (e2 + 1.f);   // 0.5*tanh(sr)
          ldsum += s;
          float y2 = fmaf(zhi[j], __expf(s), tt);
          zhi[j] = zlo[j];                   // new x2 half = old x1
          zlo[j] = y2;                       // new x1 half = y2
        }
      if (lay < NLAYERS - 1) {
        int cn = 63 - cl;                    // next layer's owned column
#pragma unroll
        for (int m2 = 0; m2 < 2; ++m2)       // stage next layer's x1 (bf16)
#pragma unroll
          for (int r = 0; r < 4; ++r) {
            int row = rbase + 16 * m2 + r;
            bufA[row * SA + cn] = f2bf(zlo[m2 * 4 + r]);
          }
        __syncthreads();                     // B3: bufA staged; h2 reads done
      }
    }
  }

  { // store z (c_6 = cB after 6 label flips)
    float* ob = outz + (size_t)t0 * DD;
#pragma unroll
    for (int m2 = 0; m2 < 2; ++m2)
#pragma unroll
      for (int r = 0; r < 4; ++r) {
        int j = m2 * 4 + r;
        int row = rbase + 16 * m2 + r;
        ob[row * DD + cB]      = zlo[j];
        ob[row * DD + 64 + cB] = zhi[j];
      }
  }
  // logdet: wave shuffle-reduce -> block -> one atomic (4 blocks/batch, commutative)
#pragma unroll
  for (int off = 32; off > 0; off >>= 1) ldsum += __shfl_down(ldsum, off);
  if (lane == 0) red[wave] = ldsum;
  __syncthreads();
  if (tid == 0) {
    float s = red[0] + red[1] + red[2] + red[3];
    atomicAdd(&outld[batch], s);
  }
}

extern "C" void kernel_launch(void* const* d_in, const int* in_sizes, int n_in,
                              void* d_out, int out_size, void* d_ws, size_t ws_size,
                              hipStream_t stream)
{
  (void)in_sizes; (void)n_in; (void)out_size; (void)ws_size;
  const float* x   = (const float*)d_in[0];
  const float* cnd = (const float*)d_in[1];
  const float* W1  = (const float*)d_in[2];
  const float* b1  = (const float*)d_in[3];
  const float* W2  = (const float*)d_in[4];
  const float* b2  = (const float*)d_in[5];
  const float* W3  = (const float*)d_in[6];
  const float* b3  = (const float*)d_in[7];
  float* outz  = (float*)d_out;
  float* outld = outz + (size_t)512 * 128 * 128;
  short* wp = (short*)d_ws;                            // 1.38 MB packed bf16 weights
  float* c1 = (float*)((char*)d_ws + (2u << 20));      // 3.1 MB fp32 cond-bias

  hipMemsetAsync(outld, 0, 512 * sizeof(float), stream);
  prep_weights<<<336, 256, 0, stream>>>(W1, W2, W3, wp);
  prep_c1<<<6 * 512, 256, 0, stream>>>(cnd, W1, b1, c1);
  flow_kernel<<<2048, NTHR, 0, stream>>>(x, c1, b2, b3, wp, outz, outld);
}

// Round 17
// 147.389 us; speedup vs baseline: 2.0165x; 1.0850x over previous
//
#include <hip/hip_runtime.h>
#include <stdint.h>

#define NLAYERS 6
#define DD      128   // patch dim
#define CONDD   128
#define HID     256
#define DIN     192
#define TM      32    // tokens per block (4-wave blocks)
#define NTHR    256   // 4 waves
#define SA      72    // bufA row stride (elements): 64 + 8 pad
#define SB      264   // bufB/C row stride (elements): 256 + 8 pad

typedef __attribute__((ext_vector_type(4))) float f32x4;
typedef __attribute__((ext_vector_type(8))) short short8;

// packed-weight geometry (16x16x32 bf16 MFMA B-fragments)
#define G1_KS 2
#define G2_KS 8
#define G3_KS 8
#define G1_FR (G1_KS*16)             // 32 frags
#define G2_FR (G2_KS*16)             // 128
#define G3_FR (G3_KS*8)              // 64
#define FR_L  (G1_FR+G2_FR+G3_FR)    // 224 frags / layer
#define EL_L  (FR_L*512)             // bf16 elems / layer
#define G2_OFF (G1_FR*512)
#define G3_OFF ((G1_FR+G2_FR)*512)

#define PW_BLOCKS 336                // weight-pack part: 336*256 = 86016 threads
#define C1_BPB    4                  // batches per block in c1 part
#define C1_BLOCKS (NLAYERS * 512 / C1_BPB)   // 768

__device__ __forceinline__ short f2bf(float f) {   // fp32 -> bf16 (RNE), scalar
  uint32_t u = __builtin_bit_cast(uint32_t, f);
  u += 0x7fffu + ((u >> 16) & 1u);
  return (short)(u >> 16);
}
// HW packed convert: dst = {bf16(hi),bf16(lo)} in one instruction
__device__ __forceinline__ uint32_t cvtpk(float lo, float hi) {
  uint32_t r;
  asm("v_cvt_pk_bf16_f32 %0, %1, %2" : "=v"(r) : "v"(lo), "v"(hi));
  return r;
}
// κ⁻¹: phys position p in a κ-packed 256-wide h-buffer -> logical feature index
__device__ __forceinline__ int kinv(int p) {
  return (p & ~63) | (p & 32) | ((p & 1) << 4) | ((p >> 1) & 15);
}

// Fused prep: blocks [0,PW_BLOCKS) pack weights into bf16 MFMA B-fragment
// layout (W2/W3 K-rows κ⁻¹-permuted; W3 cols σ_l-paired for label-flip
// coupling). Blocks [PW_BLOCKS, +C1_BLOCKS) compute the cond-bias
// c1[lay][b][h] = cond[b] @ W1[lay][64:192][h] + b1[lay][h], 4 batches per
// block (4 independent FMA chains; W re-read traffic /4 vs 1-batch blocks;
// cond indices are thread-uniform -> scalar loads).
__global__ void prep_fused(const float* __restrict__ W1,
                           const float* __restrict__ W2,
                           const float* __restrict__ W3,
                           const float* __restrict__ cond,
                           const float* __restrict__ b1,
                           short* __restrict__ wp, float* __restrict__ c1)
{
  if (blockIdx.x < PW_BLOCKS) {
    int t = blockIdx.x * 256 + threadIdx.x;      // 6*224*64 = 86016 threads exactly
    int lay  = t / (FR_L * 64);
    int rem  = t - lay * (FR_L * 64);
    int frag = rem >> 6;
    int lane = rem & 63;
    const float* src;
    int N, f2, dstbase, nfr, perm;
    if (frag < G1_FR) {
      f2 = frag;                  src = W1 + (size_t)lay * DIN * HID; N = HID; dstbase = 0;      nfr = 16; perm = 0;
    } else if (frag < G1_FR + G2_FR) {
      f2 = frag - G1_FR;          src = W2 + (size_t)lay * HID * HID; N = HID; dstbase = G2_OFF; nfr = 16; perm = 1;
    } else {
      f2 = frag - (G1_FR + G2_FR);src = W3 + (size_t)lay * HID * DD;  N = DD;  dstbase = G3_OFF; nfr = 8;  perm = 2;
    }
    int ks = f2 / nfr, nf = f2 - ks * nfr;
    int lv = lane & 15;
    int n;
    if (perm == 2) {               // σ_l: pair (s,t) for the same logical col c_l
      int g = nf >> 1, h = nf & 1;
      int c = 16 * g + lv;
      if (lay & 1) c = 63 - c;
      n = c + 64 * h;
    } else {
      n = nf * 16 + lv;
    }
    int k0 = ks * 32 + (lane >> 4) * 8;
    short8 v;
#pragma unroll
    for (int j = 0; j < 8; ++j) {
      int k = perm ? kinv(k0 + j) : (k0 + j);
      v[j] = f2bf(src[(size_t)k * N + n]);
    }
    *(short8*)(wp + (size_t)lay * EL_L + dstbase + ((size_t)f2 * 64 + lane) * 8) = v;
  } else {
    int bb  = blockIdx.x - PW_BLOCKS;        // 0..767
    int lay = bb / (512 / C1_BPB);
    int bq  = bb - lay * (512 / C1_BPB);     // batch quad
    int h   = threadIdx.x;
    const float* wb  = W1 + (size_t)lay * DIN * HID + 64 * HID + h;
    const float* cb  = cond + (size_t)(C1_BPB * bq) * CONDD;
    float bias = b1[lay * HID + h];
    float a0 = bias, a1 = bias, a2 = bias, a3 = bias;
#pragma unroll 4
    for (int c = 0; c < CONDD; ++c) {
      float w = wb[(size_t)c * HID];
      a0 = fmaf(cb[c],       w, a0);
      a1 = fmaf(cb[c + 128], w, a1);
      a2 = fmaf(cb[c + 256], w, a2);
      a3 = fmaf(cb[c + 384], w, a3);
    }
    size_t base = ((size_t)lay * 512 + C1_BPB * bq) * HID + h;
    c1[base]           = a0;
    c1[base + HID]     = a1;
    c1[base + 2 * HID] = a2;
    c1[base + 3 * HID] = a3;
  }
}

__global__ __launch_bounds__(NTHR, 4)
void flow_kernel(const float* __restrict__ x,
                 const float* __restrict__ c1g, const float* __restrict__ b2g,
                 const float* __restrict__ b3g, const short* __restrict__ wp,
                 float* __restrict__ outz, float* __restrict__ outld)
{
  // Best verified configuration (R11/R16): TM=32 / 4-wave blocks, 38.9KB LDS
  // -> 4 independent barrier domains/CU at the 128-VGPR/4-wave budget,
  // row-padded LDS (immediate-offset addressing, no XOR math), bias folded
  // into MFMA accumulator init, label-flip coupling (zero cross-lane traffic).
  __shared__ alignas(16) short bufA[TM * SA];    // x1 bf16.          4.5KB
  __shared__ alignas(16) short bufB[TM * SB];    // h1 bf16 κ-packed. 16.5KB
  __shared__ alignas(16) short bufC[TM * SB];    // h2 bf16 κ-packed. 16.5KB
  __shared__ float red[4];

  const int tid  = threadIdx.x;
  const int wave = tid >> 6;                 // = col-quarter nq (0..3)
  const int lane = tid & 63;
  const int l15  = lane & 15;
  const int l4   = lane >> 4;
  const int nq   = wave;
  const int t0   = blockIdx.x * TM;
  const int batch = t0 >> 7;                 // 4 blocks per batch

  // z ownership: thread holds the dim-pair (c_l, 64+c_l) of its 8 rows,
  // c_0 = 16*nq + l15, c_{l+1} = 63 - c_l (label flip, no data motion).
  const int cB = 16 * nq + l15;
  const int rbase = 4 * l4;                  // rows rbase + 16*m2 + r (0..31)
  float zlo[8], zhi[8];
  {
    const float* xb = x + (size_t)t0 * DD;
#pragma unroll
    for (int m2 = 0; m2 < 2; ++m2)
#pragma unroll
      for (int r = 0; r < 4; ++r) {
        int j = m2 * 4 + r;
        int row = rbase + 16 * m2 + r;
        zlo[j] = xb[row * DD + cB];
        zhi[j] = xb[row * DD + 64 + cB];
      }
#pragma unroll
    for (int m2 = 0; m2 < 2; ++m2)           // stage x1 (bf16) for layer 0
#pragma unroll
      for (int r = 0; r < 4; ++r) {
        int row = rbase + 16 * m2 + r;
        bufA[row * SA + cB] = f2bf(zlo[m2 * 4 + r]);
      }
  }
  float ldsum = 0.f;
  __syncthreads();

#pragma unroll 1
  for (int lay = 0; lay < NLAYERS; ++lay) {
    const short* wl = wp + (size_t)lay * EL_L;
    const int cl = (lay & 1) ? (63 - cB) : cB;   // this layer's owned column

    // ---- GEMM1: [32x64] @ W1a[64x256], bias acc-init, relu -> bufB (κ) ----
    {
      const float* c1row = c1g + ((size_t)lay * 512 + batch) * HID;
      f32x4 acc[2][4];
#pragma unroll
      for (int nf = 0; nf < 4; ++nf) {       // acc init = bias (C/D col = lane&15)
        float b = c1row[64 * nq + 16 * nf + l15];
        f32x4 bi = {b, b, b, b};
        acc[0][nf] = bi; acc[1][nf] = bi;
      }
#pragma unroll 1
      for (int ks = 0; ks < G1_KS; ++ks) {
        short8 bb[4];
#pragma unroll
        for (int nf = 0; nf < 4; ++nf)
          bb[nf] = *(const short8*)(wl + (((ks * 16 + 4 * nq + nf) * 64 + lane) * 8));
#pragma unroll
        for (int m2 = 0; m2 < 2; ++m2) {
          int row = 16 * m2 + l15;
          short8 a = *(const short8*)(bufA + row * SA + ks * 32 + l4 * 8);
#pragma unroll
          for (int nf = 0; nf < 4; ++nf)
            acc[m2][nf] = __builtin_amdgcn_mfma_f32_16x16x32_bf16(a, bb[nf], acc[m2][nf], 0, 0, 0);
        }
      }
#pragma unroll
      for (int h = 0; h < 2; ++h)
#pragma unroll
        for (int m2 = 0; m2 < 2; ++m2)
#pragma unroll
          for (int r = 0; r < 4; ++r) {
            int row = rbase + 16 * m2 + r;
            float v0 = fmaxf(acc[m2][2 * h][r], 0.f);
            float v1 = fmaxf(acc[m2][2 * h + 1][r], 0.f);
            *(uint32_t*)(bufB + row * SB + 64 * nq + 32 * h + 2 * l15) = cvtpk(v0, v1);
          }
    }
    __syncthreads();                         // B1: h1 ready

    // ---- GEMM2: bufB(h1) @ W2, bias-init, relu -> bufC (κ) ----
    {
      const short* wg = wl + G2_OFF;
      f32x4 acc[2][4];
#pragma unroll
      for (int nf = 0; nf < 4; ++nf) {
        float b = b2g[lay * HID + 64 * nq + 16 * nf + l15];
        f32x4 bi = {b, b, b, b};
        acc[0][nf] = bi; acc[1][nf] = bi;
      }
#pragma unroll 2
      for (int ks = 0; ks < G2_KS; ++ks) {
        short8 bb[4];
#pragma unroll
        for (int nf = 0; nf < 4; ++nf)
          bb[nf] = *(const short8*)(wg + (((ks * 16 + 4 * nq + nf) * 64 + lane) * 8));
#pragma unroll
        for (int m2 = 0; m2 < 2; ++m2) {
          int row = 16 * m2 + l15;
          short8 a = *(const short8*)(bufB + row * SB + ks * 32 + l4 * 8);
#pragma unroll
          for (int nf = 0; nf < 4; ++nf)
            acc[m2][nf] = __builtin_amdgcn_mfma_f32_16x16x32_bf16(a, bb[nf], acc[m2][nf], 0, 0, 0);
        }
      }
#pragma unroll
      for (int h = 0; h < 2; ++h)
#pragma unroll
        for (int m2 = 0; m2 < 2; ++m2)
#pragma unroll
          for (int r = 0; r < 4; ++r) {
            int row = rbase + 16 * m2 + r;
            float v0 = fmaxf(acc[m2][2 * h][r], 0.f);
            float v1 = fmaxf(acc[m2][2 * h + 1][r], 0.f);
            *(uint32_t*)(bufC + row * SB + 64 * nq + 32 * h + 2 * l15) = cvtpk(v0, v1);
          }
    }
    __syncthreads();                         // B2: h2 ready

    // ---- GEMM3 + coupling in registers (σ_l-paired s,t; label flip) ----
    {
      f32x4 acc3[2][2];
      {
        float bs = b3g[lay * DD + cl];
        float bt = b3g[lay * DD + 64 + cl];
        f32x4 bsi = {bs, bs, bs, bs}, bti = {bt, bt, bt, bt};
        acc3[0][0] = bsi; acc3[1][0] = bsi;
        acc3[0][1] = bti; acc3[1][1] = bti;
      }
#pragma unroll 2
      for (int ks = 0; ks < G3_KS; ++ks) {
        short8 bb[2];
#pragma unroll
        for (int nf = 0; nf < 2; ++nf)
          bb[nf] = *(const short8*)(wl + G3_OFF + (((ks * 8 + 2 * nq + nf) * 64 + lane) * 8));
#pragma unroll
        for (int m2 = 0; m2 < 2; ++m2) {
          int row = 16 * m2 + l15;
          short8 a = *(const short8*)(bufC + row * SB + ks * 32 + l4 * 8);
          acc3[m2][0] = __builtin_amdgcn_mfma_f32_16x16x32_bf16(a, bb[0], acc3[m2][0], 0, 0, 0);
          acc3[m2][1] = __builtin_amdgcn_mfma_f32_16x16x32_bf16(a, bb[1], acc3[m2][1], 0, 0, 0);
        }
      }
      // coupling: y2 = x2*exp(s)+t.  Label flip c->63-c: new (zlo,zhi) =
      // (y2, old x1) with NO cross-lane exchange.
#pragma unroll
      for (int m2 = 0; m2 < 2; ++m2)
#pragma unroll
        for (int r = 0; r < 4; ++r) {
          int j = m2 * 4 + r;
          float sr = fminf(fmaxf(acc3[m2][0][r], -8.f), 8.f);
          float tt = acc3[m2][1][r];
          float e2 = __expf(2.f * sr);
          float s  = 0.5f * (e2 - 1.f) / (e2 + 1.f);   // 0.5*tanh(sr)
          ldsum += s;
          float y2 = fmaf(zhi[j], __expf(s), tt);
          zhi[j] = zlo[j];                   // new x2 half = old x1
          zlo[j] = y2;                       // new x1 half = y2
        }
      if (lay < NLAYERS - 1) {
        int cn = 63 - cl;                    // next layer's owned column
#pragma unroll
        for (int m2 = 0; m2 < 2; ++m2)       // stage next layer's x1 (bf16)
#pragma unroll
          for (int r = 0; r < 4; ++r) {
            int row = rbase + 16 * m2 + r;
            bufA[row * SA + cn] = f2bf(zlo[m2 * 4 + r]);
          }
        __syncthreads();                     // B3: bufA staged; h2 reads done
      }
    }
  }

  { // store z (c_6 = cB after 6 label flips)
    float* ob = outz + (size_t)t0 * DD;
#pragma unroll
    for (int m2 = 0; m2 < 2; ++m2)
#pragma unroll
      for (int r = 0; r < 4; ++r) {
        int j = m2 * 4 + r;
        int row = rbase + 16 * m2 + r;
        ob[row * DD + cB]      = zlo[j];
        ob[row * DD + 64 + cB] = zhi[j];
      }
  }
  // logdet: wave shuffle-reduce -> block -> one atomic (4 blocks/batch, commutative)
#pragma unroll
  for (int off = 32; off > 0; off >>= 1) ldsum += __shfl_down(ldsum, off);
  if (lane == 0) red[wave] = ldsum;
  __syncthreads();
  if (tid == 0) {
    float s = red[0] + red[1] + red[2] + red[3];
    atomicAdd(&outld[batch], s);
  }
}

extern "C" void kernel_launch(void* const* d_in, const int* in_sizes, int n_in,
                              void* d_out, int out_size, void* d_ws, size_t ws_size,
                              hipStream_t stream)
{
  (void)in_sizes; (void)n_in; (void)out_size; (void)ws_size;
  const float* x   = (const float*)d_in[0];
  const float* cnd = (const float*)d_in[1];
  const float* W1  = (const float*)d_in[2];
  const float* b1  = (const float*)d_in[3];
  const float* W2  = (const float*)d_in[4];
  const float* b2  = (const float*)d_in[5];
  const float* W3  = (const float*)d_in[6];
  const float* b3  = (const float*)d_in[7];
  float* outz  = (float*)d_out;
  float* outld = outz + (size_t)512 * 128 * 128;
  short* wp = (short*)d_ws;                            // 1.38 MB packed bf16 weights
  float* c1 = (float*)((char*)d_ws + (2u << 20));      // 3.1 MB fp32 cond-bias

  hipMemsetAsync(outld, 0, 512 * sizeof(float), stream);
  prep_fused<<<PW_BLOCKS + C1_BLOCKS, 256, 0, stream>>>(W1, W2, W3, cnd, b1, wp, c1);
  flow_kernel<<<2048, NTHR, 0, stream>>>(x, c1, b2, b3, wp, outz, outld);
}

// Round 18
// 142.334 us; speedup vs baseline: 2.0881x; 1.0355x over previous
//
#include <hip/hip_runtime.h>
#include <stdint.h>

#define NLAYERS 6
#define DD      128   // patch dim
#define CONDD   128
#define HID     256
#define DIN     192
#define TM      32    // tokens per block (4-wave blocks)
#define NTHR    256   // 4 waves
#define SA      72    // bufA row stride (elements): 64 + 8 pad
#define SB      264   // bufB/C row stride (elements): 256 + 8 pad

typedef __attribute__((ext_vector_type(4))) float f32x4;
typedef __attribute__((ext_vector_type(8))) short short8;

// packed-weight geometry (16x16x32 bf16 MFMA B-fragments)
#define G1_KS 2
#define G2_KS 8
#define G3_KS 8
#define G1_FR (G1_KS*16)             // 32 frags
#define G2_FR (G2_KS*16)             // 128
#define G3_FR (G3_KS*8)              // 64
#define FR_L  (G1_FR+G2_FR+G3_FR)    // 224 frags / layer
#define EL_L  (FR_L*512)             // bf16 elems / layer
#define G2_OFF (G1_FR*512)
#define G3_OFF ((G1_FR+G2_FR)*512)

#define PW_BLOCKS 336                // weight-pack part: 336*256 = 86016 threads
#define C1_BPB    4                  // batches per block in c1 part
#define C1_BLOCKS (NLAYERS * 512 / C1_BPB)   // 768

__device__ __forceinline__ short f2bf(float f) {   // fp32 -> bf16 (RNE), scalar
  uint32_t u = __builtin_bit_cast(uint32_t, f);
  u += 0x7fffu + ((u >> 16) & 1u);
  return (short)(u >> 16);
}
// HW packed convert: dst = {bf16(hi),bf16(lo)} in one instruction
__device__ __forceinline__ uint32_t cvtpk(float lo, float hi) {
  uint32_t r;
  asm("v_cvt_pk_bf16_f32 %0, %1, %2" : "=v"(r) : "v"(lo), "v"(hi));
  return r;
}
// κ⁻¹: phys position p in a κ-packed 256-wide h-buffer -> logical feature index
__device__ __forceinline__ int kinv(int p) {
  return (p & ~63) | (p & 32) | ((p & 1) << 4) | ((p >> 1) & 15);
}

// Fused prep: blocks [0,PW_BLOCKS) pack weights into bf16 MFMA B-fragment
// layout (W2/W3 K-rows κ⁻¹-permuted; W3 cols σ_l-paired for label-flip
// coupling). Blocks [PW_BLOCKS, +C1_BLOCKS) compute the cond-bias
// c1[lay][b][h] = cond[b] @ W1[lay][64:192][h] + b1[lay][h], 4 batches per
// block. The final block zeroes outld (replaces the hipMemsetAsync node;
// runs before flow_kernel on the same stream -> ordering safe, and re-zeroes
// every call so graph replay stays deterministic).
__global__ void prep_fused(const float* __restrict__ W1,
                           const float* __restrict__ W2,
                           const float* __restrict__ W3,
                           const float* __restrict__ cond,
                           const float* __restrict__ b1,
                           short* __restrict__ wp, float* __restrict__ c1,
                           float* __restrict__ outld)
{
  if (blockIdx.x < PW_BLOCKS) {
    int t = blockIdx.x * 256 + threadIdx.x;      // 6*224*64 = 86016 threads exactly
    int lay  = t / (FR_L * 64);
    int rem  = t - lay * (FR_L * 64);
    int frag = rem >> 6;
    int lane = rem & 63;
    const float* src;
    int N, f2, dstbase, nfr, perm;
    if (frag < G1_FR) {
      f2 = frag;                  src = W1 + (size_t)lay * DIN * HID; N = HID; dstbase = 0;      nfr = 16; perm = 0;
    } else if (frag < G1_FR + G2_FR) {
      f2 = frag - G1_FR;          src = W2 + (size_t)lay * HID * HID; N = HID; dstbase = G2_OFF; nfr = 16; perm = 1;
    } else {
      f2 = frag - (G1_FR + G2_FR);src = W3 + (size_t)lay * HID * DD;  N = DD;  dstbase = G3_OFF; nfr = 8;  perm = 2;
    }
    int ks = f2 / nfr, nf = f2 - ks * nfr;
    int lv = lane & 15;
    int n;
    if (perm == 2) {               // σ_l: pair (s,t) for the same logical col c_l
      int g = nf >> 1, h = nf & 1;
      int c = 16 * g + lv;
      if (lay & 1) c = 63 - c;
      n = c + 64 * h;
    } else {
      n = nf * 16 + lv;
    }
    int k0 = ks * 32 + (lane >> 4) * 8;
    short8 v;
#pragma unroll
    for (int j = 0; j < 8; ++j) {
      int k = perm ? kinv(k0 + j) : (k0 + j);
      v[j] = f2bf(src[(size_t)k * N + n]);
    }
    *(short8*)(wp + (size_t)lay * EL_L + dstbase + ((size_t)f2 * 64 + lane) * 8) = v;
  } else if (blockIdx.x < PW_BLOCKS + C1_BLOCKS) {
    int bb  = blockIdx.x - PW_BLOCKS;        // 0..767
    int lay = bb / (512 / C1_BPB);
    int bq  = bb - lay * (512 / C1_BPB);     // batch quad
    int h   = threadIdx.x;
    const float* wb  = W1 + (size_t)lay * DIN * HID + 64 * HID + h;
    const float* cb  = cond + (size_t)(C1_BPB * bq) * CONDD;
    float bias = b1[lay * HID + h];
    float a0 = bias, a1 = bias, a2 = bias, a3 = bias;
#pragma unroll 4
    for (int c = 0; c < CONDD; ++c) {
      float w = wb[(size_t)c * HID];
      a0 = fmaf(cb[c],       w, a0);
      a1 = fmaf(cb[c + 128], w, a1);
      a2 = fmaf(cb[c + 256], w, a2);
      a3 = fmaf(cb[c + 384], w, a3);
    }
    size_t base = ((size_t)lay * 512 + C1_BPB * bq) * HID + h;
    c1[base]           = a0;
    c1[base + HID]     = a1;
    c1[base + 2 * HID] = a2;
    c1[base + 3 * HID] = a3;
  } else {
    // zero logdet output (512 floats) — replaces the memset node
    outld[threadIdx.x]       = 0.f;
    outld[threadIdx.x + 256] = 0.f;
  }
}

__global__ __launch_bounds__(NTHR, 4)
void flow_kernel(const float* __restrict__ x,
                 const float* __restrict__ c1g, const float* __restrict__ b2g,
                 const float* __restrict__ b3g, const short* __restrict__ wp,
                 float* __restrict__ outz, float* __restrict__ outld)
{
  // Best verified configuration (R11/R16): TM=32 / 4-wave blocks, 38.9KB LDS
  // -> 4 independent barrier domains/CU at the 128-VGPR/4-wave budget,
  // row-padded LDS (immediate-offset addressing, no XOR math), bias folded
  // into MFMA accumulator init, label-flip coupling (zero cross-lane traffic).
  __shared__ alignas(16) short bufA[TM * SA];    // x1 bf16.          4.5KB
  __shared__ alignas(16) short bufB[TM * SB];    // h1 bf16 κ-packed. 16.5KB
  __shared__ alignas(16) short bufC[TM * SB];    // h2 bf16 κ-packed. 16.5KB
  __shared__ float red[4];

  const int tid  = threadIdx.x;
  const int wave = tid >> 6;                 // = col-quarter nq (0..3)
  const int lane = tid & 63;
  const int l15  = lane & 15;
  const int l4   = lane >> 4;
  const int nq   = wave;
  const int t0   = blockIdx.x * TM;
  const int batch = t0 >> 7;                 // 4 blocks per batch

  // z ownership: thread holds the dim-pair (c_l, 64+c_l) of its 8 rows,
  // c_0 = 16*nq + l15, c_{l+1} = 63 - c_l (label flip, no data motion).
  const int cB = 16 * nq + l15;
  const int rbase = 4 * l4;                  // rows rbase + 16*m2 + r (0..31)
  float zlo[8], zhi[8];
  {
    const float* xb = x + (size_t)t0 * DD;
#pragma unroll
    for (int m2 = 0; m2 < 2; ++m2)
#pragma unroll
      for (int r = 0; r < 4; ++r) {
        int j = m2 * 4 + r;
        int row = rbase + 16 * m2 + r;
        zlo[j] = xb[row * DD + cB];
        zhi[j] = xb[row * DD + 64 + cB];
      }
#pragma unroll
    for (int m2 = 0; m2 < 2; ++m2)           // stage x1 (bf16) for layer 0
#pragma unroll
      for (int r = 0; r < 4; ++r) {
        int row = rbase + 16 * m2 + r;
        bufA[row * SA + cB] = f2bf(zlo[m2 * 4 + r]);
      }
  }
  float ldsum = 0.f;
  __syncthreads();

#pragma unroll 1
  for (int lay = 0; lay < NLAYERS; ++lay) {
    const short* wl = wp + (size_t)lay * EL_L;
    const int cl = (lay & 1) ? (63 - cB) : cB;   // this layer's owned column

    // ---- GEMM1: [32x64] @ W1a[64x256], bias acc-init, relu -> bufB (κ) ----
    {
      const float* c1row = c1g + ((size_t)lay * 512 + batch) * HID;
      f32x4 acc[2][4];
#pragma unroll
      for (int nf = 0; nf < 4; ++nf) {       // acc init = bias (C/D col = lane&15)
        float b = c1row[64 * nq + 16 * nf + l15];
        f32x4 bi = {b, b, b, b};
        acc[0][nf] = bi; acc[1][nf] = bi;
      }
#pragma unroll 1
      for (int ks = 0; ks < G1_KS; ++ks) {
        short8 bb[4];
#pragma unroll
        for (int nf = 0; nf < 4; ++nf)
          bb[nf] = *(const short8*)(wl + (((ks * 16 + 4 * nq + nf) * 64 + lane) * 8));
#pragma unroll
        for (int m2 = 0; m2 < 2; ++m2) {
          int row = 16 * m2 + l15;
          short8 a = *(const short8*)(bufA + row * SA + ks * 32 + l4 * 8);
#pragma unroll
          for (int nf = 0; nf < 4; ++nf)
            acc[m2][nf] = __builtin_amdgcn_mfma_f32_16x16x32_bf16(a, bb[nf], acc[m2][nf], 0, 0, 0);
        }
      }
#pragma unroll
      for (int h = 0; h < 2; ++h)
#pragma unroll
        for (int m2 = 0; m2 < 2; ++m2)
#pragma unroll
          for (int r = 0; r < 4; ++r) {
            int row = rbase + 16 * m2 + r;
            float v0 = fmaxf(acc[m2][2 * h][r], 0.f);
            float v1 = fmaxf(acc[m2][2 * h + 1][r], 0.f);
            *(uint32_t*)(bufB + row * SB + 64 * nq + 32 * h + 2 * l15) = cvtpk(v0, v1);
          }
    }
    __syncthreads();                         // B1: h1 ready

    // ---- GEMM2: bufB(h1) @ W2, bias-init, relu -> bufC (κ) ----
    {
      const short* wg = wl + G2_OFF;
      f32x4 acc[2][4];
#pragma unroll
      for (int nf = 0; nf < 4; ++nf) {
        float b = b2g[lay * HID + 64 * nq + 16 * nf + l15];
        f32x4 bi = {b, b, b, b};
        acc[0][nf] = bi; acc[1][nf] = bi;
      }
#pragma unroll 2
      for (int ks = 0; ks < G2_KS; ++ks) {
        short8 bb[4];
#pragma unroll
        for (int nf = 0; nf < 4; ++nf)
          bb[nf] = *(const short8*)(wg + (((ks * 16 + 4 * nq + nf) * 64 + lane) * 8));
#pragma unroll
        for (int m2 = 0; m2 < 2; ++m2) {
          int row = 16 * m2 + l15;
          short8 a = *(const short8*)(bufB + row * SB + ks * 32 + l4 * 8);
#pragma unroll
          for (int nf = 0; nf < 4; ++nf)
            acc[m2][nf] = __builtin_amdgcn_mfma_f32_16x16x32_bf16(a, bb[nf], acc[m2][nf], 0, 0, 0);
        }
      }
#pragma unroll
      for (int h = 0; h < 2; ++h)
#pragma unroll
        for (int m2 = 0; m2 < 2; ++m2)
#pragma unroll
          for (int r = 0; r < 4; ++r) {
            int row = rbase + 16 * m2 + r;
            float v0 = fmaxf(acc[m2][2 * h][r], 0.f);
            float v1 = fmaxf(acc[m2][2 * h + 1][r], 0.f);
            *(uint32_t*)(bufC + row * SB + 64 * nq + 32 * h + 2 * l15) = cvtpk(v0, v1);
          }
    }
    __syncthreads();                         // B2: h2 ready

    // ---- GEMM3 + coupling in registers (σ_l-paired s,t; label flip) ----
    {
      f32x4 acc3[2][2];
      {
        float bs = b3g[lay * DD + cl];
        float bt = b3g[lay * DD + 64 + cl];
        f32x4 bsi = {bs, bs, bs, bs}, bti = {bt, bt, bt, bt};
        acc3[0][0] = bsi; acc3[1][0] = bsi;
        acc3[0][1] = bti; acc3[1][1] = bti;
      }
#pragma unroll 2
      for (int ks = 0; ks < G3_KS; ++ks) {
        short8 bb[2];
#pragma unroll
        for (int nf = 0; nf < 2; ++nf)
          bb[nf] = *(const short8*)(wl + G3_OFF + (((ks * 8 + 2 * nq + nf) * 64 + lane) * 8));
#pragma unroll
        for (int m2 = 0; m2 < 2; ++m2) {
          int row = 16 * m2 + l15;
          short8 a = *(const short8*)(bufC + row * SB + ks * 32 + l4 * 8);
          acc3[m2][0] = __builtin_amdgcn_mfma_f32_16x16x32_bf16(a, bb[0], acc3[m2][0], 0, 0, 0);
          acc3[m2][1] = __builtin_amdgcn_mfma_f32_16x16x32_bf16(a, bb[1], acc3[m2][1], 0, 0, 0);
        }
      }
      // coupling: y2 = x2*exp(s)+t.  Label flip c->63-c: new (zlo,zhi) =
      // (y2, old x1) with NO cross-lane exchange.
#pragma unroll
      for (int m2 = 0; m2 < 2; ++m2)
#pragma unroll
        for (int r = 0; r < 4; ++r) {
          int j = m2 * 4 + r;
          float sr = fminf(fmaxf(acc3[m2][0][r], -8.f), 8.f);
          float tt = acc3[m2][1][r];
          float e2 = __expf(2.f * sr);
          float s  = 0.5f * (e2 - 1.f) / (e2 + 1.f);   // 0.5*tanh(sr)
          ldsum += s;
          float y2 = fmaf(zhi[j], __expf(s), tt);
          zhi[j] = zlo[j];                   // new x2 half = old x1
          zlo[j] = y2;                       // new x1 half = y2
        }
      if (lay < NLAYERS - 1) {
        int cn = 63 - cl;                    // next layer's owned column
#pragma unroll
        for (int m2 = 0; m2 < 2; ++m2)       // stage next layer's x1 (bf16)
#pragma unroll
          for (int r = 0; r < 4; ++r) {
            int row = rbase + 16 * m2 + r;
            bufA[row * SA + cn] = f2bf(zlo[m2 * 4 + r]);
          }
        __syncthreads();                     // B3: bufA staged; h2 reads done
      }
    }
  }

  { // store z (c_6 = cB after 6 label flips)
    float* ob = outz + (size_t)t0 * DD;
#pragma unroll
    for (int m2 = 0; m2 < 2; ++m2)
#pragma unroll
      for (int r = 0; r < 4; ++r) {
        int j = m2 * 4 + r;
        int row = rbase + 16 * m2 + r;
        ob[row * DD + cB]      = zlo[j];
        ob[row * DD + 64 + cB] = zhi[j];
      }
  }
  // logdet: wave shuffle-reduce -> block -> one atomic (4 blocks/batch, commutative)
#pragma unroll
  for (int off = 32; off > 0; off >>= 1) ldsum += __shfl_down(ldsum, off);
  if (lane == 0) red[wave] = ldsum;
  __syncthreads();
  if (tid == 0) {
    float s = red[0] + red[1] + red[2] + red[3];
    atomicAdd(&outld[batch], s);
  }
}

extern "C" void kernel_launch(void* const* d_in, const int* in_sizes, int n_in,
                              void* d_out, int out_size, void* d_ws, size_t ws_size,
                              hipStream_t stream)
{
  (void)in_sizes; (void)n_in; (void)out_size; (void)ws_size;
  const float* x   = (const float*)d_in[0];
  const float* cnd = (const float*)d_in[1];
  const float* W1  = (const float*)d_in[2];
  const float* b1  = (const float*)d_in[3];
  const float* W2  = (const float*)d_in[4];
  const float* b2  = (const float*)d_in[5];
  const float* W3  = (const float*)d_in[6];
  const float* b3  = (const float*)d_in[7];
  float* outz  = (float*)d_out;
  float* outld = outz + (size_t)512 * 128 * 128;
  short* wp = (short*)d_ws;                            // 1.38 MB packed bf16 weights
  float* c1 = (float*)((char*)d_ws + (2u << 20));      // 3.1 MB fp32 cond-bias

  prep_fused<<<PW_BLOCKS + C1_BLOCKS + 1, 256, 0, stream>>>(W1, W2, W3, cnd, b1,
                                                            wp, c1, outld);
  flow_kernel<<<2048, NTHR, 0, stream>>>(x, c1, b2, b3, wp, outz, outld);
}

// Round 19
// 142.204 us; speedup vs baseline: 2.0901x; 1.0009x over previous
//
#include <hip/hip_runtime.h>
#include <stdint.h>

#define NLAYERS 6
#define DD      128   // patch dim
#define CONDD   128
#define HID     256
#define DIN     192
#define TM      32    // tokens per block (4-wave blocks)
#define NTHR    256   // 4 waves
#define SA      72    // bufA row stride (elements): 64 + 8 pad
#define SB      264   // bufB/C row stride (elements): 256 + 8 pad

typedef __attribute__((ext_vector_type(4))) float f32x4;
typedef __attribute__((ext_vector_type(8))) short short8;

// packed-weight geometry (16x16x32 bf16 MFMA B-fragments)
#define G1_KS 2
#define G2_KS 8
#define G3_KS 8
#define G1_FR (G1_KS*16)             // 32 frags
#define G2_FR (G2_KS*16)             // 128
#define G3_FR (G3_KS*8)              // 64
#define FR_L  (G1_FR+G2_FR+G3_FR)    // 224 frags / layer
#define EL_L  (FR_L*512)             // bf16 elems / layer
#define G2_OFF (G1_FR*512)
#define G3_OFF ((G1_FR+G2_FR)*512)

#define PW_BLOCKS 336                // weight-pack part: 336*256 = 86016 threads
#define C1_BPB    4                  // batches per block in c1 part
#define C1_BLOCKS (NLAYERS * 512 / C1_BPB)   // 768

__device__ __forceinline__ short f2bf(float f) {   // fp32 -> bf16 (RNE), scalar
  uint32_t u = __builtin_bit_cast(uint32_t, f);
  u += 0x7fffu + ((u >> 16) & 1u);
  return (short)(u >> 16);
}
// HW packed convert: dst = {bf16(hi),bf16(lo)} in one instruction
__device__ __forceinline__ uint32_t cvtpk(float lo, float hi) {
  uint32_t r;
  asm("v_cvt_pk_bf16_f32 %0, %1, %2" : "=v"(r) : "v"(lo), "v"(hi));
  return r;
}
// κ⁻¹: phys position p in a κ-packed 256-wide h-buffer -> logical feature index
__device__ __forceinline__ int kinv(int p) {
  return (p & ~63) | (p & 32) | ((p & 1) << 4) | ((p >> 1) & 15);
}

// Fused prep: blocks [0,PW_BLOCKS) pack weights into bf16 MFMA B-fragment
// layout (W2/W3 K-rows κ⁻¹-permuted; W3 cols σ_l-paired for label-flip
// coupling). Blocks [PW_BLOCKS, +C1_BLOCKS) compute the cond-bias
// c1[lay][b][h] = cond[b] @ W1[lay][64:192][h] + b1[lay][h], 4 batches per
// block. The final block zeroes outld (replaces the hipMemsetAsync node).
__global__ void prep_fused(const float* __restrict__ W1,
                           const float* __restrict__ W2,
                           const float* __restrict__ W3,
                           const float* __restrict__ cond,
                           const float* __restrict__ b1,
                           short* __restrict__ wp, float* __restrict__ c1,
                           float* __restrict__ outld)
{
  if (blockIdx.x < PW_BLOCKS) {
    int t = blockIdx.x * 256 + threadIdx.x;      // 6*224*64 = 86016 threads exactly
    int lay  = t / (FR_L * 64);
    int rem  = t - lay * (FR_L * 64);
    int frag = rem >> 6;
    int lane = rem & 63;
    const float* src;
    int N, f2, dstbase, nfr, perm;
    if (frag < G1_FR) {
      f2 = frag;                  src = W1 + (size_t)lay * DIN * HID; N = HID; dstbase = 0;      nfr = 16; perm = 0;
    } else if (frag < G1_FR + G2_FR) {
      f2 = frag - G1_FR;          src = W2 + (size_t)lay * HID * HID; N = HID; dstbase = G2_OFF; nfr = 16; perm = 1;
    } else {
      f2 = frag - (G1_FR + G2_FR);src = W3 + (size_t)lay * HID * DD;  N = DD;  dstbase = G3_OFF; nfr = 8;  perm = 2;
    }
    int ks = f2 / nfr, nf = f2 - ks * nfr;
    int lv = lane & 15;
    int n;
    if (perm == 2) {               // σ_l: pair (s,t) for the same logical col c_l
      int g = nf >> 1, h = nf & 1;
      int c = 16 * g + lv;
      if (lay & 1) c = 63 - c;
      n = c + 64 * h;
    } else {
      n = nf * 16 + lv;
    }
    int k0 = ks * 32 + (lane >> 4) * 8;
    short8 v;
#pragma unroll
    for (int j = 0; j < 8; ++j) {
      int k = perm ? kinv(k0 + j) : (k0 + j);
      v[j] = f2bf(src[(size_t)k * N + n]);
    }
    *(short8*)(wp + (size_t)lay * EL_L + dstbase + ((size_t)f2 * 64 + lane) * 8) = v;
  } else if (blockIdx.x < PW_BLOCKS + C1_BLOCKS) {
    int bb  = blockIdx.x - PW_BLOCKS;        // 0..767
    int lay = bb / (512 / C1_BPB);
    int bq  = bb - lay * (512 / C1_BPB);     // batch quad
    int h   = threadIdx.x;
    const float* wb  = W1 + (size_t)lay * DIN * HID + 64 * HID + h;
    const float* cb  = cond + (size_t)(C1_BPB * bq) * CONDD;
    float bias = b1[lay * HID + h];
    float a0 = bias, a1 = bias, a2 = bias, a3 = bias;
#pragma unroll 4
    for (int c = 0; c < CONDD; ++c) {
      float w = wb[(size_t)c * HID];
      a0 = fmaf(cb[c],       w, a0);
      a1 = fmaf(cb[c + 128], w, a1);
      a2 = fmaf(cb[c + 256], w, a2);
      a3 = fmaf(cb[c + 384], w, a3);
    }
    size_t base = ((size_t)lay * 512 + C1_BPB * bq) * HID + h;
    c1[base]           = a0;
    c1[base + HID]     = a1;
    c1[base + 2 * HID] = a2;
    c1[base + 3 * HID] = a3;
  } else {
    // zero logdet output (512 floats) — replaces the memset node
    outld[threadIdx.x]       = 0.f;
    outld[threadIdx.x + 256] = 0.f;
  }
}

__global__ __launch_bounds__(NTHR, 4)
void flow_kernel(const float* __restrict__ x,
                 const float* __restrict__ c1g, const float* __restrict__ b2g,
                 const float* __restrict__ b3g, const short* __restrict__ wp,
                 float* __restrict__ outz, float* __restrict__ outld)
{
  // Best verified configuration (R11/R16): TM=32 / 4-wave blocks, 38.9KB LDS
  // -> 4 independent barrier domains/CU at the 128-VGPR/4-wave budget,
  // row-padded LDS (immediate-offset addressing, no XOR math), bias folded
  // into MFMA accumulator init, label-flip coupling (zero cross-lane traffic).
  // This round's single variable: G1 ks-loop fully unrolled (2 iters) so both
  // weight-load groups issue together at the post-B3 phase head.
  __shared__ alignas(16) short bufA[TM * SA];    // x1 bf16.          4.5KB
  __shared__ alignas(16) short bufB[TM * SB];    // h1 bf16 κ-packed. 16.5KB
  __shared__ alignas(16) short bufC[TM * SB];    // h2 bf16 κ-packed. 16.5KB
  __shared__ float red[4];

  const int tid  = threadIdx.x;
  const int wave = tid >> 6;                 // = col-quarter nq (0..3)
  const int lane = tid & 63;
  const int l15  = lane & 15;
  const int l4   = lane >> 4;
  const int nq   = wave;
  const int t0   = blockIdx.x * TM;
  const int batch = t0 >> 7;                 // 4 blocks per batch

  // z ownership: thread holds the dim-pair (c_l, 64+c_l) of its 8 rows,
  // c_0 = 16*nq + l15, c_{l+1} = 63 - c_l (label flip, no data motion).
  const int cB = 16 * nq + l15;
  const int rbase = 4 * l4;                  // rows rbase + 16*m2 + r (0..31)
  float zlo[8], zhi[8];
  {
    const float* xb = x + (size_t)t0 * DD;
#pragma unroll
    for (int m2 = 0; m2 < 2; ++m2)
#pragma unroll
      for (int r = 0; r < 4; ++r) {
        int j = m2 * 4 + r;
        int row = rbase + 16 * m2 + r;
        zlo[j] = xb[row * DD + cB];
        zhi[j] = xb[row * DD + 64 + cB];
      }
#pragma unroll
    for (int m2 = 0; m2 < 2; ++m2)           // stage x1 (bf16) for layer 0
#pragma unroll
      for (int r = 0; r < 4; ++r) {
        int row = rbase + 16 * m2 + r;
        bufA[row * SA + cB] = f2bf(zlo[m2 * 4 + r]);
      }
  }
  float ldsum = 0.f;
  __syncthreads();

#pragma unroll 1
  for (int lay = 0; lay < NLAYERS; ++lay) {
    const short* wl = wp + (size_t)lay * EL_L;
    const int cl = (lay & 1) ? (63 - cB) : cB;   // this layer's owned column

    // ---- GEMM1: [32x64] @ W1a[64x256], bias acc-init, relu -> bufB (κ) ----
    {
      const float* c1row = c1g + ((size_t)lay * 512 + batch) * HID;
      f32x4 acc[2][4];
#pragma unroll
      for (int nf = 0; nf < 4; ++nf) {       // acc init = bias (C/D col = lane&15)
        float b = c1row[64 * nq + 16 * nf + l15];
        f32x4 bi = {b, b, b, b};
        acc[0][nf] = bi; acc[1][nf] = bi;
      }
#pragma unroll
      for (int ks = 0; ks < G1_KS; ++ks) {   // FULL unroll: both ks groups issue together
        short8 bb[4];
#pragma unroll
        for (int nf = 0; nf < 4; ++nf)
          bb[nf] = *(const short8*)(wl + (((ks * 16 + 4 * nq + nf) * 64 + lane) * 8));
#pragma unroll
        for (int m2 = 0; m2 < 2; ++m2) {
          int row = 16 * m2 + l15;
          short8 a = *(const short8*)(bufA + row * SA + ks * 32 + l4 * 8);
#pragma unroll
          for (int nf = 0; nf < 4; ++nf)
            acc[m2][nf] = __builtin_amdgcn_mfma_f32_16x16x32_bf16(a, bb[nf], acc[m2][nf], 0, 0, 0);
        }
      }
#pragma unroll
      for (int h = 0; h < 2; ++h)
#pragma unroll
        for (int m2 = 0; m2 < 2; ++m2)
#pragma unroll
          for (int r = 0; r < 4; ++r) {
            int row = rbase + 16 * m2 + r;
            float v0 = fmaxf(acc[m2][2 * h][r], 0.f);
            float v1 = fmaxf(acc[m2][2 * h + 1][r], 0.f);
            *(uint32_t*)(bufB + row * SB + 64 * nq + 32 * h + 2 * l15) = cvtpk(v0, v1);
          }
    }
    __syncthreads();                         // B1: h1 ready

    // ---- GEMM2: bufB(h1) @ W2, bias-init, relu -> bufC (κ) ----
    {
      const short* wg = wl + G2_OFF;
      f32x4 acc[2][4];
#pragma unroll
      for (int nf = 0; nf < 4; ++nf) {
        float b = b2g[lay * HID + 64 * nq + 16 * nf + l15];
        f32x4 bi = {b, b, b, b};
        acc[0][nf] = bi; acc[1][nf] = bi;
      }
#pragma unroll 2
      for (int ks = 0; ks < G2_KS; ++ks) {
        short8 bb[4];
#pragma unroll
        for (int nf = 0; nf < 4; ++nf)
          bb[nf] = *(const short8*)(wg + (((ks * 16 + 4 * nq + nf) * 64 + lane) * 8));
#pragma unroll
        for (int m2 = 0; m2 < 2; ++m2) {
          int row = 16 * m2 + l15;
          short8 a = *(const short8*)(bufB + row * SB + ks * 32 + l4 * 8);
#pragma unroll
          for (int nf = 0; nf < 4; ++nf)
            acc[m2][nf] = __builtin_amdgcn_mfma_f32_16x16x32_bf16(a, bb[nf], acc[m2][nf], 0, 0, 0);
        }
      }
#pragma unroll
      for (int h = 0; h < 2; ++h)
#pragma unroll
        for (int m2 = 0; m2 < 2; ++m2)
#pragma unroll
          for (int r = 0; r < 4; ++r) {
            int row = rbase + 16 * m2 + r;
            float v0 = fmaxf(acc[m2][2 * h][r], 0.f);
            float v1 = fmaxf(acc[m2][2 * h + 1][r], 0.f);
            *(uint32_t*)(bufC + row * SB + 64 * nq + 32 * h + 2 * l15) = cvtpk(v0, v1);
          }
    }
    __syncthreads();                         // B2: h2 ready

    // ---- GEMM3 + coupling in registers (σ_l-paired s,t; label flip) ----
    {
      f32x4 acc3[2][2];
      {
        float bs = b3g[lay * DD + cl];
        float bt = b3g[lay * DD + 64 + cl];
        f32x4 bsi = {bs, bs, bs, bs}, bti = {bt, bt, bt, bt};
        acc3[0][0] = bsi; acc3[1][0] = bsi;
        acc3[0][1] = bti; acc3[1][1] = bti;
      }
#pragma unroll 2
      for (int ks = 0; ks < G3_KS; ++ks) {
        short8 bb[2];
#pragma unroll
        for (int nf = 0; nf < 2; ++nf)
          bb[nf] = *(const short8*)(wl + G3_OFF + (((ks * 8 + 2 * nq + nf) * 64 + lane) * 8));
#pragma unroll
        for (int m2 = 0; m2 < 2; ++m2) {
          int row = 16 * m2 + l15;
          short8 a = *(const short8*)(bufC + row * SB + ks * 32 + l4 * 8);
          acc3[m2][0] = __builtin_amdgcn_mfma_f32_16x16x32_bf16(a, bb[0], acc3[m2][0], 0, 0, 0);
          acc3[m2][1] = __builtin_amdgcn_mfma_f32_16x16x32_bf16(a, bb[1], acc3[m2][1], 0, 0, 0);
        }
      }
      // coupling: y2 = x2*exp(s)+t.  Label flip c->63-c: new (zlo,zhi) =
      // (y2, old x1) with NO cross-lane exchange.
#pragma unroll
      for (int m2 = 0; m2 < 2; ++m2)
#pragma unroll
        for (int r = 0; r < 4; ++r) {
          int j = m2 * 4 + r;
          float sr = fminf(fmaxf(acc3[m2][0][r], -8.f), 8.f);
          float tt = acc3[m2][1][r];
          float e2 = __expf(2.f * sr);
          float s  = 0.5f * (e2 - 1.f) / (e2 + 1.f);   // 0.5*tanh(sr)
          ldsum += s;
          float y2 = fmaf(zhi[j], __expf(s), tt);
          zhi[j] = zlo[j];                   // new x2 half = old x1
          zlo[j] = y2;                       // new x1 half = y2
        }
      if (lay < NLAYERS - 1) {
        int cn = 63 - cl;                    // next layer's owned column
#pragma unroll
        for (int m2 = 0; m2 < 2; ++m2)       // stage next layer's x1 (bf16)
#pragma unroll
          for (int r = 0; r < 4; ++r) {
            int row = rbase + 16 * m2 + r;
            bufA[row * SA + cn] = f2bf(zlo[m2 * 4 + r]);
          }
        __syncthreads();                     // B3: bufA staged; h2 reads done
      }
    }
  }

  { // store z (c_6 = cB after 6 label flips)
    float* ob = outz + (size_t)t0 * DD;
#pragma unroll
    for (int m2 = 0; m2 < 2; ++m2)
#pragma unroll
      for (int r = 0; r < 4; ++r) {
        int j = m2 * 4 + r;
        int row = rbase + 16 * m2 + r;
        ob[row * DD + cB]      = zlo[j];
        ob[row * DD + 64 + cB] = zhi[j];
      }
  }
  // logdet: wave shuffle-reduce -> block -> one atomic (4 blocks/batch, commutative)
#pragma unroll
  for (int off = 32; off > 0; off >>= 1) ldsum += __shfl_down(ldsum, off);
  if (lane == 0) red[wave] = ldsum;
  __syncthreads();
  if (tid == 0) {
    float s = red[0] + red[1] + red[2] + red[3];
    atomicAdd(&outld[batch], s);
  }
}

extern "C" void kernel_launch(void* const* d_in, const int* in_sizes, int n_in,
                              void* d_out, int out_size, void* d_ws, size_t ws_size,
                              hipStream_t stream)
{
  (void)in_sizes; (void)n_in; (void)out_size; (void)ws_size;
  const float* x   = (const float*)d_in[0];
  const float* cnd = (const float*)d_in[1];
  const float* W1  = (const float*)d_in[2];
  const float* b1  = (const float*)d_in[3];
  const float* W2  = (const float*)d_in[4];
  const float* b2  = (const float*)d_in[5];
  const float* W3  = (const float*)d_in[6];
  const float* b3  = (const float*)d_in[7];
  float* outz  = (float*)d_out;
  float* outld = outz + (size_t)512 * 128 * 128;
  short* wp = (short*)d_ws;                            // 1.38 MB packed bf16 weights
  float* c1 = (float*)((char*)d_ws + (2u << 20));      // 3.1 MB fp32 cond-bias

  prep_fused<<<PW_BLOCKS + C1_BLOCKS + 1, 256, 0, stream>>>(W1, W2, W3, cnd, b1,
                                                            wp, c1, outld);
  flow_kernel<<<2048, NTHR, 0, stream>>>(x, c1, b2, b3, wp, outz, outld);
}